// Round 1
// baseline (1693.582 us; speedup 1.0000x reference)
//
#include <hip/hip_runtime.h>
#include <stdint.h>
#include <math.h>

// BitNetAttention on MI355X (gfx950), round 0: correctness-first full pipeline.
// X(fp32)->bf16, W ternary(fp32)->bf16 (exact), bf16 MFMA GEMMs (16x16x32),
// RoPE fp32 tables, flash-causal attention, final GEMM -> fp32 out.

#define HDIM   4096
#define SEQ    2048
#define NBATCH 2
#define NROWS  (NBATCH * SEQ)   // 4096
#define NHEADS 32
#define DHEAD  128

typedef __attribute__((ext_vector_type(8))) short short8;
typedef __attribute__((ext_vector_type(4))) float f32x4;
typedef unsigned short u16;
typedef unsigned int   u32;

__device__ __forceinline__ float bf2f(u16 u) {
  union { float f; u32 i; } x; x.i = ((u32)u) << 16; return x.f;
}
__device__ __forceinline__ u16 f2bf(float f) {
  union { float f; u32 i; } x; x.f = f;
  u32 r = x.i + 0x7FFFu + ((x.i >> 16) & 1u);   // RNE
  return (u16)(r >> 16);
}

__device__ __forceinline__ void gload16(const u16* g, u16* l) {
  __builtin_amdgcn_global_load_lds(
      (const __attribute__((address_space(1))) u32*)g,
      (__attribute__((address_space(3))) u32*)l, 16, 0, 0);
}

// ---------------- fp32 -> bf16 convert (vectorized) ----------------
__global__ void f2bf_vec(const float* __restrict__ in, u16* __restrict__ out, int n4) {
  int i = blockIdx.x * blockDim.x + threadIdx.x;
  const int stride = gridDim.x * blockDim.x;
  for (; i < n4; i += stride) {
    float4 v = reinterpret_cast<const float4*>(in)[i];
    u32 lo = (u32)f2bf(v.x) | ((u32)f2bf(v.y) << 16);
    u32 hi = (u32)f2bf(v.z) | ((u32)f2bf(v.w) << 16);
    reinterpret_cast<uint2*>(out)[i] = make_uint2(lo, hi);
  }
}

// ---------------- RoPE tables [SEQ][64] fp32 ----------------
__global__ void rope_tables_k(float* __restrict__ cosT, float* __restrict__ sinT) {
  int idx = blockIdx.x * blockDim.x + threadIdx.x;
  if (idx >= SEQ * 64) return;
  int s = idx >> 6, d = idx & 63;
  float ex = (float)(2 * d) / 128.0f;
  float inv = powf(10000.0f, -ex);
  float f = (float)s * inv;
  cosT[idx] = cosf(f);
  sinT[idx] = sinf(f);
}

// ---------------- RoPE apply in-place on bf16 Q/K ----------------
__global__ void rope_apply(u16* __restrict__ Q, u16* __restrict__ K,
                           const float* __restrict__ cosT, const float* __restrict__ sinT) {
  const int row = blockIdx.x;
  u16* T = (blockIdx.y == 0) ? Q : K;
  const int pos = row & (SEQ - 1);
  for (int i = threadIdx.x; i < NHEADS * 64; i += blockDim.x) {
    const int hd = i >> 6, d = i & 63;
    const size_t base = (size_t)row * HDIM + hd * DHEAD + d;
    const float c = cosT[pos * 64 + d], s = sinT[pos * 64 + d];
    const float q0 = bf2f(T[base]), q1 = bf2f(T[base + 64]);
    T[base]      = f2bf(q0 * c - q1 * s);
    T[base + 64] = f2bf(q1 * c + q0 * s);
  }
}

// ---------------- GEMM: C[4096][4096] = (A * B^T) * scale ----------------
// A,B bf16 row-major [4096][4096]; 128x128 tile, BK=32, 4 waves (2x2),
// global_load_lds width-16 staging, 2-phase double buffer.
template<int OUTF>
__global__ __launch_bounds__(256)
void gemm_bt(const u16* __restrict__ A, const u16* __restrict__ B,
             void* __restrict__ Cout, const float* __restrict__ scale_ptr) {
  __shared__ __align__(16) u16 As[2][128 * 32];
  __shared__ __align__(16) u16 Bs[2][128 * 32];

  const int tid = threadIdx.x;
  const int w = tid >> 6;
  const int lane = tid & 63;
  const int lhi = lane >> 4, llo = lane & 15;
  const int rowBase = blockIdx.y * 128;
  const int colBase = blockIdx.x * 128;
  const float scl = scale_ptr[0];

  const int lrow_w = lane >> 2;          // 0..15 within 16-row chunk
  const int kc = (lane & 3) * 8;         // k element offset within 32

  auto stage = [&](int buf, int kt) {
    const int k0 = kt * 32;
#pragma unroll
    for (int i = 0; i < 2; ++i) {
      const int chunk = i * 4 + w;                 // 0..7, wave-uniform
      const int r = chunk * 16 + lrow_w;           // tile row 0..127 (per lane)
      gload16(A + (size_t)(rowBase + r) * HDIM + k0 + kc, &As[buf][chunk * 512]);
      gload16(B + (size_t)(colBase + r) * HDIM + k0 + kc, &Bs[buf][chunk * 512]);
    }
  };

  f32x4 acc[4][4];
#pragma unroll
  for (int m = 0; m < 4; ++m)
#pragma unroll
    for (int n = 0; n < 4; ++n) acc[m][n] = (f32x4)0.0f;

  const int arow0 = (w >> 1) * 64;
  const int bcol0 = (w & 1) * 64;

  stage(0, 0);
  int cur = 0;
  const int nkt = HDIM / 32;  // 128
  for (int kt = 0; kt < nkt; ++kt) {
    __syncthreads();                       // drains vmcnt -> buf[cur] ready
    if (kt + 1 < nkt) stage(cur ^ 1, kt + 1);
    short8 a[4], b[4];
#pragma unroll
    for (int m = 0; m < 4; ++m)
      a[m] = *reinterpret_cast<const short8*>(&As[cur][(arow0 + m * 16 + llo) * 32 + lhi * 8]);
#pragma unroll
    for (int n = 0; n < 4; ++n)
      b[n] = *reinterpret_cast<const short8*>(&Bs[cur][(bcol0 + n * 16 + llo) * 32 + lhi * 8]);
#pragma unroll
    for (int m = 0; m < 4; ++m)
#pragma unroll
      for (int n = 0; n < 4; ++n)
        acc[m][n] = __builtin_amdgcn_mfma_f32_16x16x32_bf16(a[m], b[n], acc[m][n], 0, 0, 0);
    cur ^= 1;
  }

  // epilogue: C/D layout col=lane&15, row=(lane>>4)*4+r  [m89-verified]
#pragma unroll
  for (int m = 0; m < 4; ++m)
#pragma unroll
    for (int n = 0; n < 4; ++n)
#pragma unroll
      for (int r = 0; r < 4; ++r) {
        const int row = rowBase + arow0 + m * 16 + lhi * 4 + r;
        const int col = colBase + bcol0 + n * 16 + llo;
        const float v = acc[m][n][r] * scl;
        if (OUTF) reinterpret_cast<float*>(Cout)[(size_t)row * HDIM + col] = v;
        else      reinterpret_cast<u16*>(Cout)[(size_t)row * HDIM + col] = f2bf(v);
      }
}

// ---------------- flash-causal attention ----------------
// Block: 4 waves, 64 q-rows (wave w owns rows 16w..16w+15), KV tiles of 32.
// Q hoisted to registers; K in LDS [32][136] (padded); V transposed in LDS
// [128][40]; per-wave P buffer [16][40]. S and PV via 16x16x32 bf16 MFMA.
__global__ __launch_bounds__(256)
void attn_causal(const u16* __restrict__ Q, const u16* __restrict__ K,
                 const u16* __restrict__ V, u16* __restrict__ O) {
  __shared__ __align__(16) u16 Ks[32][136];
  __shared__ __align__(16) u16 Vt[128][40];
  __shared__ __align__(16) u16 Pw[4][16][40];

  const int tid = threadIdx.x;
  const int w = tid >> 6, lane = tid & 63;
  const int lhi = lane >> 4, llo = lane & 15;
  const int bh = blockIdx.y, b = bh >> 5, h = bh & 31;
  const int qb = blockIdx.x * 64;

  const u16* Qg = Q + ((size_t)(b * SEQ + qb)) * HDIM + h * DHEAD;
  const u16* Kg = K + ((size_t)b * SEQ) * HDIM + h * DHEAD;
  const u16* Vg = V + ((size_t)b * SEQ) * HDIM + h * DHEAD;

  short8 qf[4];
#pragma unroll
  for (int dc = 0; dc < 4; ++dc)
    qf[dc] = *reinterpret_cast<const short8*>(Qg + (size_t)(w * 16 + llo) * HDIM + dc * 32 + lhi * 8);

  f32x4 o[8];
#pragma unroll
  for (int dt = 0; dt < 8; ++dt) o[dt] = (f32x4)0.0f;
  float mrow[4], lrow[4];
#pragma unroll
  for (int r = 0; r < 4; ++r) { mrow[r] = -__builtin_inff(); lrow[r] = 0.0f; }

  const float smul = 0.08838834764831845f;  // 1/sqrt(128)
  const int kvEnd = qb + 64;
  for (int kv0 = 0; kv0 < kvEnd; kv0 += 32) {
    // stage K (row-major, padded) and V (transposed)
#pragma unroll
    for (int i = 0; i < 2; ++i) {
      const int slot = i * 256 + tid;
      const int r = slot >> 4, ch = slot & 15;
      const short8 kvv = *reinterpret_cast<const short8*>(Kg + (size_t)(kv0 + r) * HDIM + ch * 8);
      *reinterpret_cast<short8*>(&Ks[r][ch * 8]) = kvv;
      const short8 vvv = *reinterpret_cast<const short8*>(Vg + (size_t)(kv0 + r) * HDIM + ch * 8);
#pragma unroll
      for (int j = 0; j < 8; ++j) Vt[ch * 8 + j][r] = (u16)(unsigned short)vvv[j];
    }
    __syncthreads();

    // S = Q K^T  (two 16-col tiles)
    f32x4 sacc[2];
    sacc[0] = (f32x4)0.0f; sacc[1] = (f32x4)0.0f;
#pragma unroll
    for (int nt = 0; nt < 2; ++nt)
#pragma unroll
      for (int dc = 0; dc < 4; ++dc) {
        const short8 kf = *reinterpret_cast<const short8*>(&Ks[nt * 16 + llo][dc * 32 + lhi * 8]);
        sacc[nt] = __builtin_amdgcn_mfma_f32_16x16x32_bf16(qf[dc], kf, sacc[nt], 0, 0, 0);
      }

    float sv[2][4];
#pragma unroll
    for (int nt = 0; nt < 2; ++nt)
#pragma unroll
      for (int r = 0; r < 4; ++r) {
        const int kcol = kv0 + nt * 16 + llo;
        const int qrow = qb + w * 16 + lhi * 4 + r;
        const float x = sacc[nt][r] * smul;
        sv[nt][r] = (kcol <= qrow) ? x : -__builtin_inff();
      }
    float rmax[4];
#pragma unroll
    for (int r = 0; r < 4; ++r) rmax[r] = fmaxf(sv[0][r], sv[1][r]);
#pragma unroll
    for (int xm = 1; xm < 16; xm <<= 1)
#pragma unroll
      for (int r = 0; r < 4; ++r) rmax[r] = fmaxf(rmax[r], __shfl_xor(rmax[r], xm));
    float p[2][4], fac[4], rsum[4];
#pragma unroll
    for (int r = 0; r < 4; ++r) {
      const float mn = fmaxf(mrow[r], rmax[r]);
      fac[r] = __expf(mrow[r] - mn);
      mrow[r] = mn;
      p[0][r] = __expf(sv[0][r] - mn);
      p[1][r] = __expf(sv[1][r] - mn);
      rsum[r] = p[0][r] + p[1][r];
    }
#pragma unroll
    for (int xm = 1; xm < 16; xm <<= 1)
#pragma unroll
      for (int r = 0; r < 4; ++r) rsum[r] += __shfl_xor(rsum[r], xm);
#pragma unroll
    for (int r = 0; r < 4; ++r) lrow[r] = lrow[r] * fac[r] + rsum[r];
#pragma unroll
    for (int dt = 0; dt < 8; ++dt)
#pragma unroll
      for (int r = 0; r < 4; ++r) o[dt][r] *= fac[r];

    // P -> per-wave LDS (C-layout rows), then PV
#pragma unroll
    for (int nt = 0; nt < 2; ++nt)
#pragma unroll
      for (int r = 0; r < 4; ++r)
        Pw[w][lhi * 4 + r][nt * 16 + llo] = f2bf(p[nt][r]);

    const short8 pf = *reinterpret_cast<const short8*>(&Pw[w][llo][lhi * 8]);
#pragma unroll
    for (int dt = 0; dt < 8; ++dt) {
      const short8 vf = *reinterpret_cast<const short8*>(&Vt[dt * 16 + llo][lhi * 8]);
      o[dt] = __builtin_amdgcn_mfma_f32_16x16x32_bf16(pf, vf, o[dt], 0, 0, 0);
    }
    __syncthreads();
  }

  u16* Og = O + ((size_t)(b * SEQ + qb)) * HDIM + h * DHEAD;
  float inv[4];
#pragma unroll
  for (int r = 0; r < 4; ++r) inv[r] = 1.0f / lrow[r];
#pragma unroll
  for (int dt = 0; dt < 8; ++dt)
#pragma unroll
    for (int r = 0; r < 4; ++r)
      Og[(size_t)(w * 16 + lhi * 4 + r) * HDIM + dt * 16 + llo] = f2bf(o[dt][r] * inv[r]);
}

// ---------------- launch ----------------
extern "C" void kernel_launch(void* const* d_in, const int* in_sizes, int n_in,
                              void* d_out, int out_size, void* d_ws, size_t ws_size,
                              hipStream_t stream) {
  (void)in_sizes; (void)n_in; (void)out_size; (void)ws_size;
  const float* hs = (const float*)d_in[0];
  // d_in[1] = attention_mask: exactly causal -1e9 -> implemented structurally
  const float* wq = (const float*)d_in[2];
  const float* wk = (const float*)d_in[3];
  const float* wv = (const float*)d_in[4];
  const float* wo = (const float*)d_in[5];
  const float* sq = (const float*)d_in[6];
  const float* sk = (const float*)d_in[7];
  const float* sv = (const float*)d_in[8];
  const float* so = (const float*)d_in[9];

  char* p = (char*)d_ws;
  const size_t MAT = (size_t)NROWS * HDIM * sizeof(u16);  // 32 MiB
  u16* Xb = (u16*)p; p += MAT;   // X bf16; reused as attention output
  u16* Wb = (u16*)p; p += MAT;   // current weight bf16 (reused 4x)
  u16* Qb = (u16*)p; p += MAT;
  u16* Kb = (u16*)p; p += MAT;
  u16* Vb = (u16*)p; p += MAT;
  float* cosT = (float*)p; p += (size_t)SEQ * 64 * sizeof(float);
  float* sinT = (float*)p; p += (size_t)SEQ * 64 * sizeof(float);

  const int n4 = NROWS * (HDIM / 4);
  const dim3 cb(256);
  const dim3 gg(HDIM / 128, NROWS / 128);  // 32 x 32

  f2bf_vec<<<dim3(2048), cb, 0, stream>>>(hs, Xb, n4);
  rope_tables_k<<<dim3((SEQ * 64 + 255) / 256), cb, 0, stream>>>(cosT, sinT);

  f2bf_vec<<<dim3(2048), cb, 0, stream>>>(wq, Wb, n4);
  gemm_bt<0><<<gg, cb, 0, stream>>>(Xb, Wb, (void*)Qb, sq);
  f2bf_vec<<<dim3(2048), cb, 0, stream>>>(wk, Wb, n4);
  gemm_bt<0><<<gg, cb, 0, stream>>>(Xb, Wb, (void*)Kb, sk);
  f2bf_vec<<<dim3(2048), cb, 0, stream>>>(wv, Wb, n4);
  gemm_bt<0><<<gg, cb, 0, stream>>>(Xb, Wb, (void*)Vb, sv);

  rope_apply<<<dim3(NROWS, 2), cb, 0, stream>>>(Qb, Kb, cosT, sinT);
  attn_causal<<<dim3(SEQ / 64, NBATCH * NHEADS), cb, 0, stream>>>(Qb, Kb, Vb, Xb);

  f2bf_vec<<<dim3(2048), cb, 0, stream>>>(wo, Wb, n4);
  gemm_bt<1><<<gg, cb, 0, stream>>>(Xb, Wb, d_out, so);
}

// Round 3
// 1316.731 us; speedup vs baseline: 1.2862x; 1.2862x over previous
//
#include <hip/hip_runtime.h>
#include <stdint.h>
#include <math.h>

// BitNetAttention on MI355X (gfx950), round 2: revert PV to round-0-verified
// MFMA fragment math; kill V-transpose bank conflicts via a global V^T
// pre-transpose + conflict-free b128 LDS staging/reads (bank-analyzed).

#define HDIM   4096
#define SEQ    2048
#define NBATCH 2
#define NROWS  (NBATCH * SEQ)   // 4096
#define NHEADS 32
#define DHEAD  128

typedef __attribute__((ext_vector_type(8))) short short8;
typedef __attribute__((ext_vector_type(4))) float f32x4;
typedef unsigned short u16;
typedef unsigned int   u32;

__device__ __forceinline__ float bf2f(u16 u) {
  union { float f; u32 i; } x; x.i = ((u32)u) << 16; return x.f;
}
__device__ __forceinline__ u16 f2bf(float f) {
  union { float f; u32 i; } x; x.f = f;
  u32 r = x.i + 0x7FFFu + ((x.i >> 16) & 1u);   // RNE
  return (u16)(r >> 16);
}

__device__ __forceinline__ void gload16(const u16* g, u16* l) {
  __builtin_amdgcn_global_load_lds(
      (const __attribute__((address_space(1))) u32*)g,
      (__attribute__((address_space(3))) u32*)l, 16, 0, 0);
}

__device__ __forceinline__ void unpack2(u32 v, float& a, float& b) {
  a = bf2f((u16)(v & 0xffffu)); b = bf2f((u16)(v >> 16));
}
__device__ __forceinline__ u32 pack2(float a, float b) {
  return (u32)f2bf(a) | ((u32)f2bf(b) << 16);
}

// ---------------- fp32 -> bf16 convert (vectorized) ----------------
__global__ void f2bf_vec(const float* __restrict__ in, u16* __restrict__ out, int n4) {
  int i = blockIdx.x * blockDim.x + threadIdx.x;
  const int stride = gridDim.x * blockDim.x;
  for (; i < n4; i += stride) {
    float4 v = reinterpret_cast<const float4*>(in)[i];
    u32 lo = (u32)f2bf(v.x) | ((u32)f2bf(v.y) << 16);
    u32 hi = (u32)f2bf(v.z) | ((u32)f2bf(v.w) << 16);
    reinterpret_cast<uint2*>(out)[i] = make_uint2(lo, hi);
  }
}

// ---------------- RoPE tables [SEQ][64] fp32 ----------------
__global__ void rope_tables_k(float* __restrict__ cosT, float* __restrict__ sinT) {
  int idx = blockIdx.x * blockDim.x + threadIdx.x;
  if (idx >= SEQ * 64) return;
  int s = idx >> 6, d = idx & 63;
  float ex = (float)(2 * d) / 128.0f;
  float inv = powf(10000.0f, -ex);
  float f = (float)s * inv;
  cosT[idx] = cosf(f);
  sinT[idx] = sinf(f);
}

// ---------------- RoPE apply in-place on bf16 Q/K (vectorized) ----------------
__global__ void rope_apply(u16* __restrict__ Q, u16* __restrict__ K,
                           const float* __restrict__ cosT, const float* __restrict__ sinT) {
  const int row = blockIdx.x;
  u16* T = (blockIdx.y == 0) ? Q : K;
  const int pos = row & (SEQ - 1);
  for (int i = threadIdx.x; i < NHEADS * 16; i += blockDim.x) {
    const int hd = i >> 4, d0 = (i & 15) * 4;
    const size_t base = (size_t)row * HDIM + hd * DHEAD + d0;
    uint2 alo = *reinterpret_cast<const uint2*>(&T[base]);
    uint2 ahi = *reinterpret_cast<const uint2*>(&T[base + 64]);
    float4 c4 = *reinterpret_cast<const float4*>(&cosT[pos * 64 + d0]);
    float4 s4 = *reinterpret_cast<const float4*>(&sinT[pos * 64 + d0]);
    float l0, l1, l2, l3, h0, h1, h2, h3;
    unpack2(alo.x, l0, l1); unpack2(alo.y, l2, l3);
    unpack2(ahi.x, h0, h1); unpack2(ahi.y, h2, h3);
    uint2 olo, ohi;
    olo.x = pack2(l0 * c4.x - h0 * s4.x, l1 * c4.y - h1 * s4.y);
    olo.y = pack2(l2 * c4.z - h2 * s4.z, l3 * c4.w - h3 * s4.w);
    ohi.x = pack2(h0 * c4.x + l0 * s4.x, h1 * c4.y + l1 * s4.y);
    ohi.y = pack2(h2 * c4.z + l2 * s4.z, h3 * c4.w + l3 * s4.w);
    *reinterpret_cast<uint2*>(&T[base]) = olo;
    *reinterpret_cast<uint2*>(&T[base + 64]) = ohi;
  }
}

// ---------------- V global transpose: V[b*S+s][h*128+d] -> VT[bh][d][s] ----------------
__global__ void transpose_v(const u16* __restrict__ V, u16* __restrict__ VT) {
  __shared__ u16 t[32][33];
  const int bh = blockIdx.z;               // b*32+h
  const int b = bh >> 5, h = bh & 31;
  const int s0 = blockIdx.y * 32, d0 = blockIdx.x * 32;
  const int tx = threadIdx.x;
  for (int r = threadIdx.y; r < 32; r += 8)
    t[r][tx] = V[(size_t)(b * SEQ + s0 + r) * HDIM + h * DHEAD + d0 + tx];
  __syncthreads();
  for (int r = threadIdx.y; r < 32; r += 8)
    VT[((size_t)bh * DHEAD + d0 + r) * SEQ + s0 + tx] = t[tx][r];
}

// ---------------- GEMM: C[4096][4096] = (A * B^T) * scale ----------------
template<int OUTF>
__global__ __launch_bounds__(256)
void gemm_bt(const u16* __restrict__ A, const u16* __restrict__ B,
             void* __restrict__ Cout, const float* __restrict__ scale_ptr) {
  __shared__ __align__(16) u16 As[2][128 * 32];
  __shared__ __align__(16) u16 Bs[2][128 * 32];

  const int tid = threadIdx.x;
  const int w = tid >> 6;
  const int lane = tid & 63;
  const int lhi = lane >> 4, llo = lane & 15;
  const int rowBase = blockIdx.y * 128;
  const int colBase = blockIdx.x * 128;
  const float scl = scale_ptr[0];

  const int lrow_w = lane >> 2;
  const int kc = (lane & 3) * 8;

  auto stage = [&](int buf, int kt) {
    const int k0 = kt * 32;
#pragma unroll
    for (int i = 0; i < 2; ++i) {
      const int chunk = i * 4 + w;
      const int r = chunk * 16 + lrow_w;
      gload16(A + (size_t)(rowBase + r) * HDIM + k0 + kc, &As[buf][chunk * 512]);
      gload16(B + (size_t)(colBase + r) * HDIM + k0 + kc, &Bs[buf][chunk * 512]);
    }
  };

  f32x4 acc[4][4];
#pragma unroll
  for (int m = 0; m < 4; ++m)
#pragma unroll
    for (int n = 0; n < 4; ++n) acc[m][n] = (f32x4)0.0f;

  const int arow0 = (w >> 1) * 64;
  const int bcol0 = (w & 1) * 64;

  stage(0, 0);
  int cur = 0;
  const int nkt = HDIM / 32;
  for (int kt = 0; kt < nkt; ++kt) {
    __syncthreads();
    if (kt + 1 < nkt) stage(cur ^ 1, kt + 1);
    short8 a[4], b[4];
#pragma unroll
    for (int m = 0; m < 4; ++m)
      a[m] = *reinterpret_cast<const short8*>(&As[cur][(arow0 + m * 16 + llo) * 32 + lhi * 8]);
#pragma unroll
    for (int n = 0; n < 4; ++n)
      b[n] = *reinterpret_cast<const short8*>(&Bs[cur][(bcol0 + n * 16 + llo) * 32 + lhi * 8]);
#pragma unroll
    for (int m = 0; m < 4; ++m)
#pragma unroll
      for (int n = 0; n < 4; ++n)
        acc[m][n] = __builtin_amdgcn_mfma_f32_16x16x32_bf16(a[m], b[n], acc[m][n], 0, 0, 0);
    cur ^= 1;
  }

#pragma unroll
  for (int m = 0; m < 4; ++m)
#pragma unroll
    for (int n = 0; n < 4; ++n)
#pragma unroll
      for (int r = 0; r < 4; ++r) {
        const int row = rowBase + arow0 + m * 16 + lhi * 4 + r;
        const int col = colBase + bcol0 + n * 16 + llo;
        const float v = acc[m][n][r] * scl;
        if (OUTF) reinterpret_cast<float*>(Cout)[(size_t)row * HDIM + col] = v;
        else      reinterpret_cast<u16*>(Cout)[(size_t)row * HDIM + col] = f2bf(v);
      }
}

// ---------------- flash-causal attention ----------------
// 4 waves x 16 q-rows, KV tiles of 32. Q in registers; K row-major LDS
// [32][136]; V^T (from pre-transposed global VT) in LDS [128][40] via b128
// stores (conflict-free); P via per-wave [16][40]. Round-0-verified fragments.
__global__ __launch_bounds__(256)
void attn_causal(const u16* __restrict__ Q, const u16* __restrict__ K,
                 const u16* __restrict__ VT, u16* __restrict__ O) {
  __shared__ __align__(16) u16 Ks[32][136];
  __shared__ __align__(16) u16 Vt[128][40];
  __shared__ __align__(16) u16 Pw[4][16][40];

  const int tid = threadIdx.x;
  const int w = tid >> 6, lane = tid & 63;
  const int lhi = lane >> 4, llo = lane & 15;
  const int bh = blockIdx.y, b = bh >> 5, h = bh & 31;
  const int qb = ((int)gridDim.x - 1 - (int)blockIdx.x) * 64;   // heavy blocks first

  const u16* Qg = Q + ((size_t)(b * SEQ + qb)) * HDIM + h * DHEAD;
  const u16* Kg = K + ((size_t)b * SEQ) * HDIM + h * DHEAD;
  const u16* VTg = VT + (size_t)bh * DHEAD * SEQ;   // [d][s]

  short8 qf[4];
#pragma unroll
  for (int dc = 0; dc < 4; ++dc)
    qf[dc] = *reinterpret_cast<const short8*>(Qg + (size_t)(w * 16 + llo) * HDIM + dc * 32 + lhi * 8);

  f32x4 o[8];
#pragma unroll
  for (int dt = 0; dt < 8; ++dt) o[dt] = (f32x4)0.0f;
  float mrow[4], lrow[4];
#pragma unroll
  for (int r = 0; r < 4; ++r) { mrow[r] = -__builtin_inff(); lrow[r] = 0.0f; }

  const float smul = 0.08838834764831845f;  // 1/sqrt(128)
  const int kvEnd = qb + 64;
  for (int kv0 = 0; kv0 < kvEnd; kv0 += 32) {
    // stage K row-major padded (b128 stores, conflict-free: bank=4(lhi+llo)+16w)
#pragma unroll
    for (int i = 0; i < 2; ++i) {
      const int slot = i * 256 + tid;
      const int r = slot >> 4, ch = slot & 15;
      const short8 kvv = *reinterpret_cast<const short8*>(Kg + (size_t)(kv0 + r) * HDIM + ch * 8);
      *reinterpret_cast<short8*>(&Ks[r][ch * 8]) = kvv;
    }
    // stage V^T rows from global VT (b128 stores, bank start=20d+4ko: conflict-free)
#pragma unroll
    for (int i = 0; i < 2; ++i) {
      const int idx = i * 256 + tid;
      const int d = idx >> 2, ko = idx & 3;
      const short8 vvv = *reinterpret_cast<const short8*>(VTg + (size_t)d * SEQ + kv0 + ko * 8);
      *reinterpret_cast<short8*>(&Vt[d][ko * 8]) = vvv;
    }
    __syncthreads();

    // S = Q K^T  (two 16-col tiles)
    f32x4 sacc[2];
    sacc[0] = (f32x4)0.0f; sacc[1] = (f32x4)0.0f;
#pragma unroll
    for (int nt = 0; nt < 2; ++nt)
#pragma unroll
      for (int dc = 0; dc < 4; ++dc) {
        const short8 kf = *reinterpret_cast<const short8*>(&Ks[nt * 16 + llo][dc * 32 + lhi * 8]);
        sacc[nt] = __builtin_amdgcn_mfma_f32_16x16x32_bf16(qf[dc], kf, sacc[nt], 0, 0, 0);
      }

    float sv[2][4];
#pragma unroll
    for (int nt = 0; nt < 2; ++nt)
#pragma unroll
      for (int r = 0; r < 4; ++r) {
        const int kcol = kv0 + nt * 16 + llo;
        const int qrow = qb + w * 16 + lhi * 4 + r;
        const float x = sacc[nt][r] * smul;
        sv[nt][r] = (kcol <= qrow) ? x : -__builtin_inff();
      }
    float rmax[4];
#pragma unroll
    for (int r = 0; r < 4; ++r) rmax[r] = fmaxf(sv[0][r], sv[1][r]);
#pragma unroll
    for (int xm = 1; xm < 16; xm <<= 1)
#pragma unroll
      for (int r = 0; r < 4; ++r) rmax[r] = fmaxf(rmax[r], __shfl_xor(rmax[r], xm));
    float p[2][4], fac[4], rsum[4];
#pragma unroll
    for (int r = 0; r < 4; ++r) {
      const float mn = fmaxf(mrow[r], rmax[r]);
      fac[r] = __expf(mrow[r] - mn);
      mrow[r] = mn;
      p[0][r] = __expf(sv[0][r] - mn);
      p[1][r] = __expf(sv[1][r] - mn);
      rsum[r] = p[0][r] + p[1][r];
    }
#pragma unroll
    for (int xm = 1; xm < 16; xm <<= 1)
#pragma unroll
      for (int r = 0; r < 4; ++r) rsum[r] += __shfl_xor(rsum[r], xm);
#pragma unroll
    for (int r = 0; r < 4; ++r) lrow[r] = lrow[r] * fac[r] + rsum[r];
#pragma unroll
    for (int dt = 0; dt < 8; ++dt)
#pragma unroll
      for (int r = 0; r < 4; ++r) o[dt][r] *= fac[r];

    // P -> per-wave LDS (round-0-verified layout)
#pragma unroll
    for (int nt = 0; nt < 2; ++nt)
#pragma unroll
      for (int r = 0; r < 4; ++r)
        Pw[w][lhi * 4 + r][nt * 16 + llo] = f2bf(p[nt][r]);

    const short8 pf = *reinterpret_cast<const short8*>(&Pw[w][llo][lhi * 8]);
#pragma unroll
    for (int dt = 0; dt < 8; ++dt) {
      const short8 vf = *reinterpret_cast<const short8*>(&Vt[dt * 16 + llo][lhi * 8]);
      o[dt] = __builtin_amdgcn_mfma_f32_16x16x32_bf16(pf, vf, o[dt], 0, 0, 0);
    }
    __syncthreads();
  }

  u16* Og = O + ((size_t)(b * SEQ + qb)) * HDIM + h * DHEAD;
  float inv[4];
#pragma unroll
  for (int r = 0; r < 4; ++r) inv[r] = 1.0f / lrow[r];
#pragma unroll
  for (int dt = 0; dt < 8; ++dt)
#pragma unroll
    for (int r = 0; r < 4; ++r)
      Og[(size_t)(w * 16 + lhi * 4 + r) * HDIM + dt * 16 + llo] = f2bf(o[dt][r] * inv[r]);
}

// ---------------- launch ----------------
extern "C" void kernel_launch(void* const* d_in, const int* in_sizes, int n_in,
                              void* d_out, int out_size, void* d_ws, size_t ws_size,
                              hipStream_t stream) {
  (void)in_sizes; (void)n_in; (void)out_size; (void)ws_size;
  const float* hs = (const float*)d_in[0];
  const float* wq = (const float*)d_in[2];
  const float* wk = (const float*)d_in[3];
  const float* wv = (const float*)d_in[4];
  const float* wo = (const float*)d_in[5];
  const float* sq = (const float*)d_in[6];
  const float* sk = (const float*)d_in[7];
  const float* sv = (const float*)d_in[8];
  const float* so = (const float*)d_in[9];

  char* p = (char*)d_ws;
  const size_t MAT = (size_t)NROWS * HDIM * sizeof(u16);  // 32 MiB
  u16* Xb = (u16*)p; p += MAT;   // X bf16; later attention output
  u16* Wb = (u16*)p; p += MAT;   // weight bf16 slot; holds VT during attention
  u16* Qb = (u16*)p; p += MAT;
  u16* Kb = (u16*)p; p += MAT;
  u16* Vb = (u16*)p; p += MAT;
  float* cosT = (float*)p; p += (size_t)SEQ * 64 * sizeof(float);
  float* sinT = (float*)p; p += (size_t)SEQ * 64 * sizeof(float);

  const int n4 = NROWS * (HDIM / 4);
  const dim3 cb(256);
  const dim3 gg(HDIM / 128, NROWS / 128);

  f2bf_vec<<<dim3(2048), cb, 0, stream>>>(hs, Xb, n4);
  rope_tables_k<<<dim3((SEQ * 64 + 255) / 256), cb, 0, stream>>>(cosT, sinT);

  f2bf_vec<<<dim3(2048), cb, 0, stream>>>(wq, Wb, n4);
  gemm_bt<0><<<gg, cb, 0, stream>>>(Xb, Wb, (void*)Qb, sq);
  f2bf_vec<<<dim3(2048), cb, 0, stream>>>(wk, Wb, n4);
  gemm_bt<0><<<gg, cb, 0, stream>>>(Xb, Wb, (void*)Kb, sk);
  f2bf_vec<<<dim3(2048), cb, 0, stream>>>(wv, Wb, n4);
  gemm_bt<0><<<gg, cb, 0, stream>>>(Xb, Wb, (void*)Vb, sv);

  rope_apply<<<dim3(NROWS, 2), cb, 0, stream>>>(Qb, Kb, cosT, sinT);
  // V^T into Wb slot (wv no longer needed); then attention reads it
  transpose_v<<<dim3(DHEAD / 32, SEQ / 32, NBATCH * NHEADS), dim3(32, 8), 0, stream>>>(Vb, Wb);
  attn_causal<<<dim3(SEQ / 64, NBATCH * NHEADS), cb, 0, stream>>>(Qb, Kb, Wb, Xb);

  f2bf_vec<<<dim3(2048), cb, 0, stream>>>(wo, Wb, n4);
  gemm_bt<1><<<gg, cb, 0, stream>>>(Xb, Wb, d_out, so);
}

// Round 4
// 1244.244 us; speedup vs baseline: 1.3611x; 1.0583x over previous
//
#include <hip/hip_runtime.h>
#include <stdint.h>
#include <math.h>

// BitNetAttention on MI355X (gfx950), round 3: attention latency restructure.
// QBLK=128 w/ 8 waves (halves block-iters), async reg-staged K/V prefetch
// (T14), wave-level causal compute skip, conflict-free Pw (pitch 36),
// setprio around MFMA clusters (T5). GEMM/RoPE/transpose unchanged (R2-pass).

#define HDIM   4096
#define SEQ    2048
#define NBATCH 2
#define NROWS  (NBATCH * SEQ)   // 4096
#define NHEADS 32
#define DHEAD  128
#define QBLK   128

typedef __attribute__((ext_vector_type(8))) short short8;
typedef __attribute__((ext_vector_type(4))) short short4v;
typedef __attribute__((ext_vector_type(4))) float f32x4;
typedef unsigned short u16;
typedef unsigned int   u32;

__device__ __forceinline__ float bf2f(u16 u) {
  union { float f; u32 i; } x; x.i = ((u32)u) << 16; return x.f;
}
__device__ __forceinline__ u16 f2bf(float f) {
  union { float f; u32 i; } x; x.f = f;
  u32 r = x.i + 0x7FFFu + ((x.i >> 16) & 1u);   // RNE
  return (u16)(r >> 16);
}

__device__ __forceinline__ void gload16(const u16* g, u16* l) {
  __builtin_amdgcn_global_load_lds(
      (const __attribute__((address_space(1))) u32*)g,
      (__attribute__((address_space(3))) u32*)l, 16, 0, 0);
}

__device__ __forceinline__ void unpack2(u32 v, float& a, float& b) {
  a = bf2f((u16)(v & 0xffffu)); b = bf2f((u16)(v >> 16));
}
__device__ __forceinline__ u32 pack2(float a, float b) {
  return (u32)f2bf(a) | ((u32)f2bf(b) << 16);
}

// ---------------- fp32 -> bf16 convert (vectorized) ----------------
__global__ void f2bf_vec(const float* __restrict__ in, u16* __restrict__ out, int n4) {
  int i = blockIdx.x * blockDim.x + threadIdx.x;
  const int stride = gridDim.x * blockDim.x;
  for (; i < n4; i += stride) {
    float4 v = reinterpret_cast<const float4*>(in)[i];
    u32 lo = (u32)f2bf(v.x) | ((u32)f2bf(v.y) << 16);
    u32 hi = (u32)f2bf(v.z) | ((u32)f2bf(v.w) << 16);
    reinterpret_cast<uint2*>(out)[i] = make_uint2(lo, hi);
  }
}

// ---------------- RoPE tables [SEQ][64] fp32 ----------------
__global__ void rope_tables_k(float* __restrict__ cosT, float* __restrict__ sinT) {
  int idx = blockIdx.x * blockDim.x + threadIdx.x;
  if (idx >= SEQ * 64) return;
  int s = idx >> 6, d = idx & 63;
  float ex = (float)(2 * d) / 128.0f;
  float inv = powf(10000.0f, -ex);
  float f = (float)s * inv;
  cosT[idx] = cosf(f);
  sinT[idx] = sinf(f);
}

// ---------------- RoPE apply in-place on bf16 Q/K (vectorized) ----------------
__global__ void rope_apply(u16* __restrict__ Q, u16* __restrict__ K,
                           const float* __restrict__ cosT, const float* __restrict__ sinT) {
  const int row = blockIdx.x;
  u16* T = (blockIdx.y == 0) ? Q : K;
  const int pos = row & (SEQ - 1);
  for (int i = threadIdx.x; i < NHEADS * 16; i += blockDim.x) {
    const int hd = i >> 4, d0 = (i & 15) * 4;
    const size_t base = (size_t)row * HDIM + hd * DHEAD + d0;
    uint2 alo = *reinterpret_cast<const uint2*>(&T[base]);
    uint2 ahi = *reinterpret_cast<const uint2*>(&T[base + 64]);
    float4 c4 = *reinterpret_cast<const float4*>(&cosT[pos * 64 + d0]);
    float4 s4 = *reinterpret_cast<const float4*>(&sinT[pos * 64 + d0]);
    float l0, l1, l2, l3, h0, h1, h2, h3;
    unpack2(alo.x, l0, l1); unpack2(alo.y, l2, l3);
    unpack2(ahi.x, h0, h1); unpack2(ahi.y, h2, h3);
    uint2 olo, ohi;
    olo.x = pack2(l0 * c4.x - h0 * s4.x, l1 * c4.y - h1 * s4.y);
    olo.y = pack2(l2 * c4.z - h2 * s4.z, l3 * c4.w - h3 * s4.w);
    ohi.x = pack2(h0 * c4.x + l0 * s4.x, h1 * c4.y + l1 * s4.y);
    ohi.y = pack2(h2 * c4.z + l2 * s4.z, h3 * c4.w + l3 * s4.w);
    *reinterpret_cast<uint2*>(&T[base]) = olo;
    *reinterpret_cast<uint2*>(&T[base + 64]) = ohi;
  }
}

// ---------------- V global transpose: V[b*S+s][h*128+d] -> VT[bh][d][s] ----------------
__global__ void transpose_v(const u16* __restrict__ V, u16* __restrict__ VT) {
  __shared__ u16 t[32][33];
  const int bh = blockIdx.z;               // b*32+h
  const int b = bh >> 5, h = bh & 31;
  const int s0 = blockIdx.y * 32, d0 = blockIdx.x * 32;
  const int tx = threadIdx.x;
  for (int r = threadIdx.y; r < 32; r += 8)
    t[r][tx] = V[(size_t)(b * SEQ + s0 + r) * HDIM + h * DHEAD + d0 + tx];
  __syncthreads();
  for (int r = threadIdx.y; r < 32; r += 8)
    VT[((size_t)bh * DHEAD + d0 + r) * SEQ + s0 + tx] = t[tx][r];
}

// ---------------- GEMM: C[4096][4096] = (A * B^T) * scale ----------------
template<int OUTF>
__global__ __launch_bounds__(256)
void gemm_bt(const u16* __restrict__ A, const u16* __restrict__ B,
             void* __restrict__ Cout, const float* __restrict__ scale_ptr) {
  __shared__ __align__(16) u16 As[2][128 * 32];
  __shared__ __align__(16) u16 Bs[2][128 * 32];

  const int tid = threadIdx.x;
  const int w = tid >> 6;
  const int lane = tid & 63;
  const int lhi = lane >> 4, llo = lane & 15;
  const int rowBase = blockIdx.y * 128;
  const int colBase = blockIdx.x * 128;
  const float scl = scale_ptr[0];

  const int lrow_w = lane >> 2;
  const int kc = (lane & 3) * 8;

  auto stage = [&](int buf, int kt) {
    const int k0 = kt * 32;
#pragma unroll
    for (int i = 0; i < 2; ++i) {
      const int chunk = i * 4 + w;
      const int r = chunk * 16 + lrow_w;
      gload16(A + (size_t)(rowBase + r) * HDIM + k0 + kc, &As[buf][chunk * 512]);
      gload16(B + (size_t)(colBase + r) * HDIM + k0 + kc, &Bs[buf][chunk * 512]);
    }
  };

  f32x4 acc[4][4];
#pragma unroll
  for (int m = 0; m < 4; ++m)
#pragma unroll
    for (int n = 0; n < 4; ++n) acc[m][n] = (f32x4)0.0f;

  const int arow0 = (w >> 1) * 64;
  const int bcol0 = (w & 1) * 64;

  stage(0, 0);
  int cur = 0;
  const int nkt = HDIM / 32;
  for (int kt = 0; kt < nkt; ++kt) {
    __syncthreads();
    if (kt + 1 < nkt) stage(cur ^ 1, kt + 1);
    short8 a[4], b[4];
#pragma unroll
    for (int m = 0; m < 4; ++m)
      a[m] = *reinterpret_cast<const short8*>(&As[cur][(arow0 + m * 16 + llo) * 32 + lhi * 8]);
#pragma unroll
    for (int n = 0; n < 4; ++n)
      b[n] = *reinterpret_cast<const short8*>(&Bs[cur][(bcol0 + n * 16 + llo) * 32 + lhi * 8]);
#pragma unroll
    for (int m = 0; m < 4; ++m)
#pragma unroll
      for (int n = 0; n < 4; ++n)
        acc[m][n] = __builtin_amdgcn_mfma_f32_16x16x32_bf16(a[m], b[n], acc[m][n], 0, 0, 0);
    cur ^= 1;
  }

#pragma unroll
  for (int m = 0; m < 4; ++m)
#pragma unroll
    for (int n = 0; n < 4; ++n)
#pragma unroll
      for (int r = 0; r < 4; ++r) {
        const int row = rowBase + arow0 + m * 16 + lhi * 4 + r;
        const int col = colBase + bcol0 + n * 16 + llo;
        const float v = acc[m][n][r] * scl;
        if (OUTF) reinterpret_cast<float*>(Cout)[(size_t)row * HDIM + col] = v;
        else      reinterpret_cast<u16*>(Cout)[(size_t)row * HDIM + col] = f2bf(v);
      }
}

// ---------------- flash-causal attention ----------------
// 8 waves x 16 q-rows (QBLK=128), KV tiles of 32. Q in registers; K LDS
// [32][136]; V^T LDS [128][40]; Pw [8][16][36] (conflict-free stores).
// Async reg-staged K/V prefetch; wave-level causal skip; setprio on MFMA.
__global__ __launch_bounds__(512, 4)
void attn_causal(const u16* __restrict__ Q, const u16* __restrict__ K,
                 const u16* __restrict__ VT, u16* __restrict__ O) {
  __shared__ __align__(16) u16 Ks[32][136];
  __shared__ __align__(16) u16 Vt[128][40];
  __shared__ __align__(16) u16 Pw[8][16][36];

  const int tid = threadIdx.x;
  const int w = tid >> 6, lane = tid & 63;
  const int lhi = lane >> 4, llo = lane & 15;
  const int bh = blockIdx.y, b = bh >> 5, h = bh & 31;
  const int qb = ((int)gridDim.x - 1 - (int)blockIdx.x) * QBLK;  // heavy first

  const u16* Qg = Q + ((size_t)(b * SEQ + qb)) * HDIM + h * DHEAD;
  const u16* Kg = K + ((size_t)b * SEQ) * HDIM + h * DHEAD;
  const u16* VTg = VT + (size_t)bh * DHEAD * SEQ;   // [d][s]

  short8 qf[4];
#pragma unroll
  for (int dc = 0; dc < 4; ++dc)
    qf[dc] = *reinterpret_cast<const short8*>(Qg + (size_t)(w * 16 + llo) * HDIM + dc * 32 + lhi * 8);

  f32x4 o[8];
#pragma unroll
  for (int dt = 0; dt < 8; ++dt) o[dt] = (f32x4)0.0f;
  float mrow[4], lrow[4];
#pragma unroll
  for (int r = 0; r < 4; ++r) { mrow[r] = -__builtin_inff(); lrow[r] = 0.0f; }

  // staging assignments (512 threads)
  const int kr = tid >> 4, kch = tid & 15;   // K: row 0..31, 8-elem chunk 0..15
  const int vd = tid >> 2, vko = tid & 3;    // V^T: d-row 0..127, kv-chunk 0..3

  const float smul = 0.08838834764831845f;   // 1/sqrt(128)
  const int wmax = qb + w * 16 + 15;         // wave's last q-row
  const int ntile = (qb + QBLK) / 32;

  // prologue: tile 0 -> regs
  short8 kreg = *reinterpret_cast<const short8*>(Kg + (size_t)kr * HDIM + kch * 8);
  short8 vreg = *reinterpret_cast<const short8*>(VTg + (size_t)vd * SEQ + vko * 8);

  for (int t = 0; t < ntile; ++t) {
    const int kv0 = t * 32;
    __syncthreads();                                   // LDS free (prev tile done)
    *reinterpret_cast<short8*>(&Ks[kr][kch * 8]) = kreg;
    *reinterpret_cast<short8*>(&Vt[vd][vko * 8]) = vreg;
    if (t + 1 < ntile) {                               // async prefetch next tile
      kreg = *reinterpret_cast<const short8*>(Kg + (size_t)(kv0 + 32 + kr) * HDIM + kch * 8);
      vreg = *reinterpret_cast<const short8*>(VTg + (size_t)vd * SEQ + kv0 + 32 + vko * 8);
    }
    __syncthreads();                                   // tile resident

    if (kv0 <= wmax) {                                 // wave-level causal skip (exact)
      // S = Q K^T  (two 16-col tiles)
      f32x4 sacc[2];
      sacc[0] = (f32x4)0.0f; sacc[1] = (f32x4)0.0f;
      __builtin_amdgcn_s_setprio(1);
#pragma unroll
      for (int nt2 = 0; nt2 < 2; ++nt2)
#pragma unroll
        for (int dc = 0; dc < 4; ++dc) {
          const short8 kf = *reinterpret_cast<const short8*>(&Ks[nt2 * 16 + llo][dc * 32 + lhi * 8]);
          sacc[nt2] = __builtin_amdgcn_mfma_f32_16x16x32_bf16(qf[dc], kf, sacc[nt2], 0, 0, 0);
        }
      __builtin_amdgcn_s_setprio(0);

      float sv[2][4];
#pragma unroll
      for (int nt2 = 0; nt2 < 2; ++nt2)
#pragma unroll
        for (int r = 0; r < 4; ++r) {
          const int kcol = kv0 + nt2 * 16 + llo;
          const int qrow = qb + w * 16 + lhi * 4 + r;
          const float x = sacc[nt2][r] * smul;
          sv[nt2][r] = (kcol <= qrow) ? x : -__builtin_inff();
        }
      float rmax[4];
#pragma unroll
      for (int r = 0; r < 4; ++r) rmax[r] = fmaxf(sv[0][r], sv[1][r]);
#pragma unroll
      for (int xm = 1; xm < 16; xm <<= 1)
#pragma unroll
        for (int r = 0; r < 4; ++r) rmax[r] = fmaxf(rmax[r], __shfl_xor(rmax[r], xm));
      float p[2][4], fac[4], rsum[4];
#pragma unroll
      for (int r = 0; r < 4; ++r) {
        const float mn = fmaxf(mrow[r], rmax[r]);
        fac[r] = __expf(mrow[r] - mn);
        mrow[r] = mn;
        p[0][r] = __expf(sv[0][r] - mn);
        p[1][r] = __expf(sv[1][r] - mn);
        rsum[r] = p[0][r] + p[1][r];
      }
#pragma unroll
      for (int xm = 1; xm < 16; xm <<= 1)
#pragma unroll
        for (int r = 0; r < 4; ++r) rsum[r] += __shfl_xor(rsum[r], xm);
#pragma unroll
      for (int r = 0; r < 4; ++r) lrow[r] = lrow[r] * fac[r] + rsum[r];
#pragma unroll
      for (int dt = 0; dt < 8; ++dt)
#pragma unroll
        for (int r = 0; r < 4; ++r) o[dt][r] *= fac[r];

      // P -> per-wave LDS (pitch 36: store bank = 8lhi+18r+llo/2, 2 lanes/bank)
#pragma unroll
      for (int nt2 = 0; nt2 < 2; ++nt2)
#pragma unroll
        for (int r = 0; r < 4; ++r)
          Pw[w][lhi * 4 + r][nt2 * 16 + llo] = f2bf(p[nt2][r]);

      union { short4v h[2]; short8 v8; } pu;
      pu.h[0] = *reinterpret_cast<const short4v*>(&Pw[w][llo][lhi * 8]);
      pu.h[1] = *reinterpret_cast<const short4v*>(&Pw[w][llo][lhi * 8 + 4]);
      __builtin_amdgcn_s_setprio(1);
#pragma unroll
      for (int dt = 0; dt < 8; ++dt) {
        const short8 vf = *reinterpret_cast<const short8*>(&Vt[dt * 16 + llo][lhi * 8]);
        o[dt] = __builtin_amdgcn_mfma_f32_16x16x32_bf16(pu.v8, vf, o[dt], 0, 0, 0);
      }
      __builtin_amdgcn_s_setprio(0);
    }
  }

  u16* Og = O + ((size_t)(b * SEQ + qb)) * HDIM + h * DHEAD;
  float inv[4];
#pragma unroll
  for (int r = 0; r < 4; ++r) inv[r] = 1.0f / lrow[r];
#pragma unroll
  for (int dt = 0; dt < 8; ++dt)
#pragma unroll
    for (int r = 0; r < 4; ++r)
      Og[(size_t)(w * 16 + lhi * 4 + r) * HDIM + dt * 16 + llo] = f2bf(o[dt][r] * inv[r]);
}

// ---------------- launch ----------------
extern "C" void kernel_launch(void* const* d_in, const int* in_sizes, int n_in,
                              void* d_out, int out_size, void* d_ws, size_t ws_size,
                              hipStream_t stream) {
  (void)in_sizes; (void)n_in; (void)out_size; (void)ws_size;
  const float* hs = (const float*)d_in[0];
  const float* wq = (const float*)d_in[2];
  const float* wk = (const float*)d_in[3];
  const float* wv = (const float*)d_in[4];
  const float* wo = (const float*)d_in[5];
  const float* sq = (const float*)d_in[6];
  const float* sk = (const float*)d_in[7];
  const float* sv = (const float*)d_in[8];
  const float* so = (const float*)d_in[9];

  char* p = (char*)d_ws;
  const size_t MAT = (size_t)NROWS * HDIM * sizeof(u16);  // 32 MiB
  u16* Xb = (u16*)p; p += MAT;   // X bf16; later attention output
  u16* Wb = (u16*)p; p += MAT;   // weight bf16 slot; holds VT during attention
  u16* Qb = (u16*)p; p += MAT;
  u16* Kb = (u16*)p; p += MAT;
  u16* Vb = (u16*)p; p += MAT;
  float* cosT = (float*)p; p += (size_t)SEQ * 64 * sizeof(float);
  float* sinT = (float*)p; p += (size_t)SEQ * 64 * sizeof(float);

  const int n4 = NROWS * (HDIM / 4);
  const dim3 cb(256);
  const dim3 gg(HDIM / 128, NROWS / 128);

  f2bf_vec<<<dim3(2048), cb, 0, stream>>>(hs, Xb, n4);
  rope_tables_k<<<dim3((SEQ * 64 + 255) / 256), cb, 0, stream>>>(cosT, sinT);

  f2bf_vec<<<dim3(2048), cb, 0, stream>>>(wq, Wb, n4);
  gemm_bt<0><<<gg, cb, 0, stream>>>(Xb, Wb, (void*)Qb, sq);
  f2bf_vec<<<dim3(2048), cb, 0, stream>>>(wk, Wb, n4);
  gemm_bt<0><<<gg, cb, 0, stream>>>(Xb, Wb, (void*)Kb, sk);
  f2bf_vec<<<dim3(2048), cb, 0, stream>>>(wv, Wb, n4);
  gemm_bt<0><<<gg, cb, 0, stream>>>(Xb, Wb, (void*)Vb, sv);

  rope_apply<<<dim3(NROWS, 2), cb, 0, stream>>>(Qb, Kb, cosT, sinT);
  transpose_v<<<dim3(DHEAD / 32, SEQ / 32, NBATCH * NHEADS), dim3(32, 8), 0, stream>>>(Vb, Wb);
  attn_causal<<<dim3(SEQ / QBLK, NBATCH * NHEADS), dim3(512), 0, stream>>>(Qb, Kb, Wb, Xb);

  f2bf_vec<<<dim3(2048), cb, 0, stream>>>(wo, Wb, n4);
  gemm_bt<1><<<gg, cb, 0, stream>>>(Xb, Wb, d_out, so);
}

// Round 5
// 1146.271 us; speedup vs baseline: 1.4775x; 1.0855x over previous
//
#include <hip/hip_runtime.h>
#include <stdint.h>
#include <math.h>

// BitNetAttention on MI355X (gfx950), round 4: fix attention CU load
// imbalance (dispatch stride 256 = 0 mod 16 gave every CU four SAME-size
// causal blocks -> 16x work spread). Balanced size-class permutation:
// s(x,k) = {x, 15-x, (x+8)&15, (7-x)&15}, sum = 30 for all x.
// Also: V computed pre-transposed by operand-swapped GEMM (transpose_v
// kernel deleted). GEMM/RoPE unchanged.

#define HDIM   4096
#define SEQ    2048
#define NBATCH 2
#define NROWS  (NBATCH * SEQ)   // 4096
#define NHEADS 32
#define DHEAD  128
#define QBLK   128

typedef __attribute__((ext_vector_type(8))) short short8;
typedef __attribute__((ext_vector_type(4))) short short4v;
typedef __attribute__((ext_vector_type(4))) float f32x4;
typedef unsigned short u16;
typedef unsigned int   u32;

__device__ __forceinline__ float bf2f(u16 u) {
  union { float f; u32 i; } x; x.i = ((u32)u) << 16; return x.f;
}
__device__ __forceinline__ u16 f2bf(float f) {
  union { float f; u32 i; } x; x.f = f;
  u32 r = x.i + 0x7FFFu + ((x.i >> 16) & 1u);   // RNE
  return (u16)(r >> 16);
}

__device__ __forceinline__ void gload16(const u16* g, u16* l) {
  __builtin_amdgcn_global_load_lds(
      (const __attribute__((address_space(1))) u32*)g,
      (__attribute__((address_space(3))) u32*)l, 16, 0, 0);
}

__device__ __forceinline__ void unpack2(u32 v, float& a, float& b) {
  a = bf2f((u16)(v & 0xffffu)); b = bf2f((u16)(v >> 16));
}
__device__ __forceinline__ u32 pack2(float a, float b) {
  return (u32)f2bf(a) | ((u32)f2bf(b) << 16);
}

// ---------------- fp32 -> bf16 convert (vectorized) ----------------
__global__ void f2bf_vec(const float* __restrict__ in, u16* __restrict__ out, int n4) {
  int i = blockIdx.x * blockDim.x + threadIdx.x;
  const int stride = gridDim.x * blockDim.x;
  for (; i < n4; i += stride) {
    float4 v = reinterpret_cast<const float4*>(in)[i];
    u32 lo = (u32)f2bf(v.x) | ((u32)f2bf(v.y) << 16);
    u32 hi = (u32)f2bf(v.z) | ((u32)f2bf(v.w) << 16);
    reinterpret_cast<uint2*>(out)[i] = make_uint2(lo, hi);
  }
}

// ---------------- RoPE tables [SEQ][64] fp32 ----------------
__global__ void rope_tables_k(float* __restrict__ cosT, float* __restrict__ sinT) {
  int idx = blockIdx.x * blockDim.x + threadIdx.x;
  if (idx >= SEQ * 64) return;
  int s = idx >> 6, d = idx & 63;
  float ex = (float)(2 * d) / 128.0f;
  float inv = powf(10000.0f, -ex);
  float f = (float)s * inv;
  cosT[idx] = cosf(f);
  sinT[idx] = sinf(f);
}

// ---------------- RoPE apply in-place on bf16 Q/K (vectorized) ----------------
__global__ void rope_apply(u16* __restrict__ Q, u16* __restrict__ K,
                           const float* __restrict__ cosT, const float* __restrict__ sinT) {
  const int row = blockIdx.x;
  u16* T = (blockIdx.y == 0) ? Q : K;
  const int pos = row & (SEQ - 1);
  for (int i = threadIdx.x; i < NHEADS * 16; i += blockDim.x) {
    const int hd = i >> 4, d0 = (i & 15) * 4;
    const size_t base = (size_t)row * HDIM + hd * DHEAD + d0;
    uint2 alo = *reinterpret_cast<const uint2*>(&T[base]);
    uint2 ahi = *reinterpret_cast<const uint2*>(&T[base + 64]);
    float4 c4 = *reinterpret_cast<const float4*>(&cosT[pos * 64 + d0]);
    float4 s4 = *reinterpret_cast<const float4*>(&sinT[pos * 64 + d0]);
    float l0, l1, l2, l3, h0, h1, h2, h3;
    unpack2(alo.x, l0, l1); unpack2(alo.y, l2, l3);
    unpack2(ahi.x, h0, h1); unpack2(ahi.y, h2, h3);
    uint2 olo, ohi;
    olo.x = pack2(l0 * c4.x - h0 * s4.x, l1 * c4.y - h1 * s4.y);
    olo.y = pack2(l2 * c4.z - h2 * s4.z, l3 * c4.w - h3 * s4.w);
    ohi.x = pack2(h0 * c4.x + l0 * s4.x, h1 * c4.y + l1 * s4.y);
    ohi.y = pack2(h2 * c4.z + l2 * s4.z, h3 * c4.w + l3 * s4.w);
    *reinterpret_cast<uint2*>(&T[base]) = olo;
    *reinterpret_cast<uint2*>(&T[base + 64]) = ohi;
  }
}

// ---------------- GEMM: C[4096][4096] = (A * B^T) * scale ----------------
template<int OUTF>
__global__ __launch_bounds__(256)
void gemm_bt(const u16* __restrict__ A, const u16* __restrict__ B,
             void* __restrict__ Cout, const float* __restrict__ scale_ptr) {
  __shared__ __align__(16) u16 As[2][128 * 32];
  __shared__ __align__(16) u16 Bs[2][128 * 32];

  const int tid = threadIdx.x;
  const int w = tid >> 6;
  const int lane = tid & 63;
  const int lhi = lane >> 4, llo = lane & 15;
  const int rowBase = blockIdx.y * 128;
  const int colBase = blockIdx.x * 128;
  const float scl = scale_ptr[0];

  const int lrow_w = lane >> 2;
  const int kc = (lane & 3) * 8;

  auto stage = [&](int buf, int kt) {
    const int k0 = kt * 32;
#pragma unroll
    for (int i = 0; i < 2; ++i) {
      const int chunk = i * 4 + w;
      const int r = chunk * 16 + lrow_w;
      gload16(A + (size_t)(rowBase + r) * HDIM + k0 + kc, &As[buf][chunk * 512]);
      gload16(B + (size_t)(colBase + r) * HDIM + k0 + kc, &Bs[buf][chunk * 512]);
    }
  };

  f32x4 acc[4][4];
#pragma unroll
  for (int m = 0; m < 4; ++m)
#pragma unroll
    for (int n = 0; n < 4; ++n) acc[m][n] = (f32x4)0.0f;

  const int arow0 = (w >> 1) * 64;
  const int bcol0 = (w & 1) * 64;

  stage(0, 0);
  int cur = 0;
  const int nkt = HDIM / 32;
  for (int kt = 0; kt < nkt; ++kt) {
    __syncthreads();
    if (kt + 1 < nkt) stage(cur ^ 1, kt + 1);
    short8 a[4], b[4];
#pragma unroll
    for (int m = 0; m < 4; ++m)
      a[m] = *reinterpret_cast<const short8*>(&As[cur][(arow0 + m * 16 + llo) * 32 + lhi * 8]);
#pragma unroll
    for (int n = 0; n < 4; ++n)
      b[n] = *reinterpret_cast<const short8*>(&Bs[cur][(bcol0 + n * 16 + llo) * 32 + lhi * 8]);
#pragma unroll
    for (int m = 0; m < 4; ++m)
#pragma unroll
      for (int n = 0; n < 4; ++n)
        acc[m][n] = __builtin_amdgcn_mfma_f32_16x16x32_bf16(a[m], b[n], acc[m][n], 0, 0, 0);
    cur ^= 1;
  }

#pragma unroll
  for (int m = 0; m < 4; ++m)
#pragma unroll
    for (int n = 0; n < 4; ++n)
#pragma unroll
      for (int r = 0; r < 4; ++r) {
        const int row = rowBase + arow0 + m * 16 + lhi * 4 + r;
        const int col = colBase + bcol0 + n * 16 + llo;
        const float v = acc[m][n][r] * scl;
        if (OUTF) reinterpret_cast<float*>(Cout)[(size_t)row * HDIM + col] = v;
        else      reinterpret_cast<u16*>(Cout)[(size_t)row * HDIM + col] = f2bf(v);
      }
}

// ---------------- flash-causal attention ----------------
// 8 waves x 16 q-rows (QBLK=128). Balanced size-class permutation:
// k=y>>4, s(x,k) in {x, 15-x, (x+8)&15, (7-x)&15} -> per-CU tile totals equal.
// V^T comes straight from the operand-swapped GEMM (row-stride NROWS).
__global__ __launch_bounds__(512, 4)
void attn_causal(const u16* __restrict__ Q, const u16* __restrict__ K,
                 const u16* __restrict__ VT, u16* __restrict__ O) {
  __shared__ __align__(16) u16 Ks[32][136];
  __shared__ __align__(16) u16 Vt[128][40];
  __shared__ __align__(16) u16 Pw[8][16][36];

  const int tid = threadIdx.x;
  const int w = tid >> 6, lane = tid & 63;
  const int lhi = lane >> 4, llo = lane & 15;
  const int bh = blockIdx.y, b = bh >> 5, h = bh & 31;

  // balanced size-class permutation (bijective in x for each k; sum const)
  const int x = blockIdx.x, kcl = blockIdx.y >> 4;
  int s;
  if (kcl == 0)      s = x;
  else if (kcl == 1) s = 15 - x;
  else if (kcl == 2) s = (x + 8) & 15;
  else               s = (7 - x) & 15;
  const int qb = s * QBLK;

  const u16* Qg = Q + ((size_t)(b * SEQ + qb)) * HDIM + h * DHEAD;
  const u16* Kg = K + ((size_t)b * SEQ) * HDIM + h * DHEAD;
  const u16* VTg = VT + (size_t)(h * DHEAD) * NROWS + b * SEQ;  // [d][s], stride NROWS

  short8 qf[4];
#pragma unroll
  for (int dc = 0; dc < 4; ++dc)
    qf[dc] = *reinterpret_cast<const short8*>(Qg + (size_t)(w * 16 + llo) * HDIM + dc * 32 + lhi * 8);

  f32x4 o[8];
#pragma unroll
  for (int dt = 0; dt < 8; ++dt) o[dt] = (f32x4)0.0f;
  float mrow[4], lrow[4];
#pragma unroll
  for (int r = 0; r < 4; ++r) { mrow[r] = -__builtin_inff(); lrow[r] = 0.0f; }

  // staging assignments (512 threads)
  const int kr = tid >> 4, kch = tid & 15;   // K: row 0..31, 8-elem chunk 0..15
  const int vd = tid >> 2, vko = tid & 3;    // V^T: d-row 0..127, kv-chunk 0..3

  const float smul = 0.08838834764831845f;   // 1/sqrt(128)
  const int wmax = qb + w * 16 + 15;         // wave's last q-row
  const int ntile = (qb + QBLK) / 32;

  // prologue: tile 0 -> regs
  short8 kreg = *reinterpret_cast<const short8*>(Kg + (size_t)kr * HDIM + kch * 8);
  short8 vreg = *reinterpret_cast<const short8*>(VTg + (size_t)vd * NROWS + vko * 8);

  for (int t = 0; t < ntile; ++t) {
    const int kv0 = t * 32;
    __syncthreads();                                   // LDS free (prev tile done)
    *reinterpret_cast<short8*>(&Ks[kr][kch * 8]) = kreg;
    *reinterpret_cast<short8*>(&Vt[vd][vko * 8]) = vreg;
    if (t + 1 < ntile) {                               // prefetch next tile
      kreg = *reinterpret_cast<const short8*>(Kg + (size_t)(kv0 + 32 + kr) * HDIM + kch * 8);
      vreg = *reinterpret_cast<const short8*>(VTg + (size_t)vd * NROWS + kv0 + 32 + vko * 8);
    }
    __syncthreads();                                   // tile resident

    if (kv0 <= wmax) {                                 // wave-level causal skip (exact)
      f32x4 sacc[2];
      sacc[0] = (f32x4)0.0f; sacc[1] = (f32x4)0.0f;
      __builtin_amdgcn_s_setprio(1);
#pragma unroll
      for (int nt2 = 0; nt2 < 2; ++nt2)
#pragma unroll
        for (int dc = 0; dc < 4; ++dc) {
          const short8 kf = *reinterpret_cast<const short8*>(&Ks[nt2 * 16 + llo][dc * 32 + lhi * 8]);
          sacc[nt2] = __builtin_amdgcn_mfma_f32_16x16x32_bf16(qf[dc], kf, sacc[nt2], 0, 0, 0);
        }
      __builtin_amdgcn_s_setprio(0);

      float sv[2][4];
#pragma unroll
      for (int nt2 = 0; nt2 < 2; ++nt2)
#pragma unroll
        for (int r = 0; r < 4; ++r) {
          const int kcol = kv0 + nt2 * 16 + llo;
          const int qrow = qb + w * 16 + lhi * 4 + r;
          const float xv = sacc[nt2][r] * smul;
          sv[nt2][r] = (kcol <= qrow) ? xv : -__builtin_inff();
        }
      float rmax[4];
#pragma unroll
      for (int r = 0; r < 4; ++r) rmax[r] = fmaxf(sv[0][r], sv[1][r]);
#pragma unroll
      for (int xm = 1; xm < 16; xm <<= 1)
#pragma unroll
        for (int r = 0; r < 4; ++r) rmax[r] = fmaxf(rmax[r], __shfl_xor(rmax[r], xm));
      float p[2][4], fac[4], rsum[4];
#pragma unroll
      for (int r = 0; r < 4; ++r) {
        const float mn = fmaxf(mrow[r], rmax[r]);
        fac[r] = __expf(mrow[r] - mn);
        mrow[r] = mn;
        p[0][r] = __expf(sv[0][r] - mn);
        p[1][r] = __expf(sv[1][r] - mn);
        rsum[r] = p[0][r] + p[1][r];
      }
#pragma unroll
      for (int xm = 1; xm < 16; xm <<= 1)
#pragma unroll
        for (int r = 0; r < 4; ++r) rsum[r] += __shfl_xor(rsum[r], xm);
#pragma unroll
      for (int r = 0; r < 4; ++r) lrow[r] = lrow[r] * fac[r] + rsum[r];
#pragma unroll
      for (int dt = 0; dt < 8; ++dt)
#pragma unroll
        for (int r = 0; r < 4; ++r) o[dt][r] *= fac[r];

      // P -> per-wave LDS (pitch 36)
#pragma unroll
      for (int nt2 = 0; nt2 < 2; ++nt2)
#pragma unroll
        for (int r = 0; r < 4; ++r)
          Pw[w][lhi * 4 + r][nt2 * 16 + llo] = f2bf(p[nt2][r]);

      union { short4v hh[2]; short8 v8; } pu;
      pu.hh[0] = *reinterpret_cast<const short4v*>(&Pw[w][llo][lhi * 8]);
      pu.hh[1] = *reinterpret_cast<const short4v*>(&Pw[w][llo][lhi * 8 + 4]);
      __builtin_amdgcn_s_setprio(1);
#pragma unroll
      for (int dt = 0; dt < 8; ++dt) {
        const short8 vf = *reinterpret_cast<const short8*>(&Vt[dt * 16 + llo][lhi * 8]);
        o[dt] = __builtin_amdgcn_mfma_f32_16x16x32_bf16(pu.v8, vf, o[dt], 0, 0, 0);
      }
      __builtin_amdgcn_s_setprio(0);
    }
  }

  u16* Og = O + ((size_t)(b * SEQ + qb)) * HDIM + h * DHEAD;
  float inv[4];
#pragma unroll
  for (int r = 0; r < 4; ++r) inv[r] = 1.0f / lrow[r];
#pragma unroll
  for (int dt = 0; dt < 8; ++dt)
#pragma unroll
    for (int r = 0; r < 4; ++r)
      Og[(size_t)(w * 16 + lhi * 4 + r) * HDIM + dt * 16 + llo] = f2bf(o[dt][r] * inv[r]);
}

// ---------------- launch ----------------
extern "C" void kernel_launch(void* const* d_in, const int* in_sizes, int n_in,
                              void* d_out, int out_size, void* d_ws, size_t ws_size,
                              hipStream_t stream) {
  (void)in_sizes; (void)n_in; (void)out_size; (void)ws_size;
  const float* hs = (const float*)d_in[0];
  const float* wq = (const float*)d_in[2];
  const float* wk = (const float*)d_in[3];
  const float* wv = (const float*)d_in[4];
  const float* wo = (const float*)d_in[5];
  const float* sq = (const float*)d_in[6];
  const float* sk = (const float*)d_in[7];
  const float* sv = (const float*)d_in[8];
  const float* so = (const float*)d_in[9];

  char* p = (char*)d_ws;
  const size_t MAT = (size_t)NROWS * HDIM * sizeof(u16);  // 32 MiB
  u16* Xb = (u16*)p; p += MAT;   // X bf16; later attention output
  u16* Wb = (u16*)p; p += MAT;   // weight bf16 slot (reused 4x)
  u16* Qb = (u16*)p; p += MAT;
  u16* Kb = (u16*)p; p += MAT;
  u16* Vb = (u16*)p; p += MAT;   // holds V^T (operand-swapped GEMM output)
  float* cosT = (float*)p; p += (size_t)SEQ * 64 * sizeof(float);
  float* sinT = (float*)p; p += (size_t)SEQ * 64 * sizeof(float);

  const int n4 = NROWS * (HDIM / 4);
  const dim3 cb(256);
  const dim3 gg(HDIM / 128, NROWS / 128);

  f2bf_vec<<<dim3(2048), cb, 0, stream>>>(hs, Xb, n4);
  rope_tables_k<<<dim3((SEQ * 64 + 255) / 256), cb, 0, stream>>>(cosT, sinT);

  f2bf_vec<<<dim3(2048), cb, 0, stream>>>(wq, Wb, n4);
  gemm_bt<0><<<gg, cb, 0, stream>>>(Xb, Wb, (void*)Qb, sq);
  f2bf_vec<<<dim3(2048), cb, 0, stream>>>(wk, Wb, n4);
  gemm_bt<0><<<gg, cb, 0, stream>>>(Xb, Wb, (void*)Kb, sk);
  f2bf_vec<<<dim3(2048), cb, 0, stream>>>(wv, Wb, n4);
  // operand-swapped: C[o][r] = sum_k Wv[o][k] X[r][k] = V^T  (into Vb)
  gemm_bt<0><<<gg, cb, 0, stream>>>(Wb, Xb, (void*)Vb, sv);

  rope_apply<<<dim3(NROWS, 2), cb, 0, stream>>>(Qb, Kb, cosT, sinT);
  attn_causal<<<dim3(SEQ / QBLK, NBATCH * NHEADS), dim3(512), 0, stream>>>(Qb, Kb, Vb, Xb);

  f2bf_vec<<<dim3(2048), cb, 0, stream>>>(wo, Wb, n4);
  gemm_bt<1><<<gg, cb, 0, stream>>>(Xb, Wb, d_out, so);
}

// Round 6
// 846.315 us; speedup vs baseline: 2.0011x; 1.3544x over previous
//
#include <hip/hip_runtime.h>
#include <stdint.h>
#include <math.h>

// BitNetAttention on MI355X (gfx950), round 5: replace 128^2 2-phase GEMM
// (m97-structure, ~912 TF ceiling) with a 256^2 / BK=64 / 8-wave 8-phase
// schedule (counted vmcnt(4), raw s_barrier, XOR-swizzled LDS reads,
// pre-swizzled global_load_lds staging). Attn/RoPE/converts unchanged (R4).

#define HDIM   4096
#define SEQ    2048
#define NBATCH 2
#define NROWS  (NBATCH * SEQ)   // 4096
#define NHEADS 32
#define DHEAD  128
#define QBLK   128

typedef __attribute__((ext_vector_type(8))) short short8;
typedef __attribute__((ext_vector_type(4))) short short4v;
typedef __attribute__((ext_vector_type(4))) float f32x4;
typedef unsigned short u16;
typedef unsigned int   u32;

__device__ __forceinline__ float bf2f(u16 u) {
  union { float f; u32 i; } x; x.i = ((u32)u) << 16; return x.f;
}
__device__ __forceinline__ u16 f2bf(float f) {
  union { float f; u32 i; } x; x.f = f;
  u32 r = x.i + 0x7FFFu + ((x.i >> 16) & 1u);   // RNE
  return (u16)(r >> 16);
}

__device__ __forceinline__ void gload16(const u16* g, u16* l) {
  __builtin_amdgcn_global_load_lds(
      (const __attribute__((address_space(1))) u32*)g,
      (__attribute__((address_space(3))) u32*)l, 16, 0, 0);
}

__device__ __forceinline__ void unpack2(u32 v, float& a, float& b) {
  a = bf2f((u16)(v & 0xffffu)); b = bf2f((u16)(v >> 16));
}
__device__ __forceinline__ u32 pack2(float a, float b) {
  return (u32)f2bf(a) | ((u32)f2bf(b) << 16);
}

// ---------------- fp32 -> bf16 convert (vectorized) ----------------
__global__ void f2bf_vec(const float* __restrict__ in, u16* __restrict__ out, int n4) {
  int i = blockIdx.x * blockDim.x + threadIdx.x;
  const int stride = gridDim.x * blockDim.x;
  for (; i < n4; i += stride) {
    float4 v = reinterpret_cast<const float4*>(in)[i];
    u32 lo = (u32)f2bf(v.x) | ((u32)f2bf(v.y) << 16);
    u32 hi = (u32)f2bf(v.z) | ((u32)f2bf(v.w) << 16);
    reinterpret_cast<uint2*>(out)[i] = make_uint2(lo, hi);
  }
}

// ---------------- RoPE tables [SEQ][64] fp32 ----------------
__global__ void rope_tables_k(float* __restrict__ cosT, float* __restrict__ sinT) {
  int idx = blockIdx.x * blockDim.x + threadIdx.x;
  if (idx >= SEQ * 64) return;
  int s = idx >> 6, d = idx & 63;
  float ex = (float)(2 * d) / 128.0f;
  float inv = powf(10000.0f, -ex);
  float f = (float)s * inv;
  cosT[idx] = cosf(f);
  sinT[idx] = sinf(f);
}

// ---------------- RoPE apply in-place on bf16 Q/K (vectorized) ----------------
__global__ void rope_apply(u16* __restrict__ Q, u16* __restrict__ K,
                           const float* __restrict__ cosT, const float* __restrict__ sinT) {
  const int row = blockIdx.x;
  u16* T = (blockIdx.y == 0) ? Q : K;
  const int pos = row & (SEQ - 1);
  for (int i = threadIdx.x; i < NHEADS * 16; i += blockDim.x) {
    const int hd = i >> 4, d0 = (i & 15) * 4;
    const size_t base = (size_t)row * HDIM + hd * DHEAD + d0;
    uint2 alo = *reinterpret_cast<const uint2*>(&T[base]);
    uint2 ahi = *reinterpret_cast<const uint2*>(&T[base + 64]);
    float4 c4 = *reinterpret_cast<const float4*>(&cosT[pos * 64 + d0]);
    float4 s4 = *reinterpret_cast<const float4*>(&sinT[pos * 64 + d0]);
    float l0, l1, l2, l3, h0, h1, h2, h3;
    unpack2(alo.x, l0, l1); unpack2(alo.y, l2, l3);
    unpack2(ahi.x, h0, h1); unpack2(ahi.y, h2, h3);
    uint2 olo, ohi;
    olo.x = pack2(l0 * c4.x - h0 * s4.x, l1 * c4.y - h1 * s4.y);
    olo.y = pack2(l2 * c4.z - h2 * s4.z, l3 * c4.w - h3 * s4.w);
    ohi.x = pack2(h0 * c4.x + l0 * s4.x, h1 * c4.y + l1 * s4.y);
    ohi.y = pack2(h2 * c4.z + l2 * s4.z, h3 * c4.w + l3 * s4.w);
    *reinterpret_cast<uint2*>(&T[base]) = olo;
    *reinterpret_cast<uint2*>(&T[base + 64]) = ohi;
  }
}

// ---------------- 8-phase GEMM: C[4096][4096] = (A * B^T) * scale ----------------
// 256x256 tile, BK=64, 8 waves (2x4), 512 thr, 128 KiB dynamic LDS.
// LDS (u16 units): A at [0,32768): [buf][mhalf][128 r][64 k]; B at +32768 same.
// Read swizzle: 16B-slot c -> c ^ (r&7); staging pre-swizzles the global src.
// Phase: 12 ds_read_b128 | stage 1 half (2 gload_lds) | s_barrier | lgkm(0) |
// setprio+16 MFMA | [vmcnt(4) @ ph4/ph8] | s_barrier.  Peeled last iter.
template<int OUTF>
__global__ __launch_bounds__(512, 2)
void gemm8(const u16* __restrict__ Am, const u16* __restrict__ Bm,
           void* __restrict__ Cout, const float* __restrict__ scale_ptr) {
  extern __shared__ __align__(16) u16 ldsp[];

  const int tid = threadIdx.x;
  const int w = tid >> 6, lane = tid & 63;
  const int llo = lane & 15, lhi = (lane >> 4) & 3;
  const int wr = w >> 2, wc = w & 3;           // 2 x 4 waves

  // XCD-rectangle block swizzle (grid = 256 1-D): each XCD gets a 4x8 rect
  const int bid = blockIdx.x;
  const int xcd = bid & 7, ii = bid >> 3;
  const int by = (xcd >> 1) * 4 + (ii & 3);
  const int bx = (xcd & 1) * 8 + (ii >> 2);
  const int rowBase = by * 256, colBase = bx * 256;
  const float scl = scale_ptr[0];

  // stage one half-tile: op (A/B), tile ts, m/n-half h. 2 x gload_lds(16B).
  auto stage_half = [&](const u16* G, int obase, int ts, int h, int opB) {
    const int p = ts & 1;
    const u32 base = (opB ? 32768u : 0u) + (u32)p * 16384u + (u32)h * 8192u;
#pragma unroll
    for (int i = 0; i < 2; ++i) {
      const int ru = i * 64 + w * 8;                 // wave-uniform row
      const int r = ru + (lane >> 3);                // per-lane row
      const int cc = (lane & 7) ^ (r & 7);           // pre-swizzled 16B chunk
      gload16(G + (size_t)(obase + h * 128 + r) * HDIM + ts * 64 + cc * 8,
              ldsp + base + (u32)ru * 64u);
    }
  };

  f32x4 acc[8][4];
#pragma unroll
  for (int m = 0; m < 8; ++m)
#pragma unroll
    for (int n = 0; n < 4; ++n) acc[m][n] = (f32x4)0.0f;

// one phase: compute quadrant (MH,NH) of tile TCUR; optional stage; waits.
#define PH(TCUR, MH, NH, TS, H, OPB, DOSTAGE, VMN) do {                          \
    const int p_ = (TCUR) & 1;                                                   \
    short8 af_[4][2]; short8 bf_[2][2];                                          \
    const u32 ab_ = (u32)(p_ * 16384 + (MH) * 8192);                             \
    const u32 bb_ = (u32)(32768 + p_ * 16384 + (NH) * 8192);                     \
    _Pragma("unroll")                                                            \
    for (int m4 = 0; m4 < 4; ++m4) { const int r_ = wr * 64 + m4 * 16 + llo;     \
      _Pragma("unroll")                                                          \
      for (int kk = 0; kk < 2; ++kk) { const int c_ = kk * 4 + lhi;              \
        af_[m4][kk] = *reinterpret_cast<const short8*>(                          \
            ldsp + ab_ + r_ * 64 + ((c_ ^ (r_ & 7)) * 8)); } }                   \
    _Pragma("unroll")                                                            \
    for (int n2 = 0; n2 < 2; ++n2) { const int r_ = wc * 32 + n2 * 16 + llo;     \
      _Pragma("unroll")                                                          \
      for (int kk = 0; kk < 2; ++kk) { const int c_ = kk * 4 + lhi;              \
        bf_[n2][kk] = *reinterpret_cast<const short8*>(                          \
            ldsp + bb_ + r_ * 64 + ((c_ ^ (r_ & 7)) * 8)); } }                   \
    if (DOSTAGE) stage_half((OPB) ? Bm : Am, (OPB) ? colBase : rowBase,          \
                            (TS), (H), (OPB));                                   \
    __builtin_amdgcn_s_barrier();                                                \
    asm volatile("s_waitcnt lgkmcnt(0)" ::: "memory");                           \
    __builtin_amdgcn_s_setprio(1);                                               \
    _Pragma("unroll")                                                            \
    for (int m4 = 0; m4 < 4; ++m4)                                               \
      _Pragma("unroll")                                                          \
      for (int n2 = 0; n2 < 2; ++n2)                                             \
        _Pragma("unroll")                                                        \
        for (int kk = 0; kk < 2; ++kk)                                           \
          acc[(MH) * 4 + m4][(NH) * 2 + n2] =                                    \
              __builtin_amdgcn_mfma_f32_16x16x32_bf16(                           \
                  af_[m4][kk], bf_[n2][kk],                                      \
                  acc[(MH) * 4 + m4][(NH) * 2 + n2], 0, 0, 0);                   \
    __builtin_amdgcn_s_setprio(0);                                               \
    if ((VMN) == 4) asm volatile("s_waitcnt vmcnt(4)" ::: "memory");             \
    if ((VMN) == 0) asm volatile("s_waitcnt vmcnt(0)" ::: "memory");             \
    __builtin_amdgcn_s_barrier();                                                \
  } while (0)

  // prologue: t0 fully + t1 halves {Ah0,Bh0}; t0 landed, 4 loads in flight
  stage_half(Am, rowBase, 0, 0, 0);
  stage_half(Bm, colBase, 0, 0, 1);
  stage_half(Am, rowBase, 0, 1, 0);
  stage_half(Bm, colBase, 0, 1, 1);
  stage_half(Am, rowBase, 1, 0, 0);
  stage_half(Bm, colBase, 1, 0, 1);
  asm volatile("s_waitcnt vmcnt(4)" ::: "memory");
  __builtin_amdgcn_s_barrier();

  // main loop: 31 iterations of 2 K-tiles (T = 2*it), fixed stage schedule:
  // ph1:(T+1)Ah1 ph2:(T+1)Bh1 ph3:(T+2)Ah0 ph4:(T+2)Bh0+vm4
  // ph5:(T+2)Ah1 ph6:(T+2)Bh1 ph7:(T+3)Ah0 ph8:(T+3)Bh0+vm4
  for (int it = 0; it < 31; ++it) {
    const int T = 2 * it;
    PH(T,     0, 0, T + 1, 1, 0, 1, -1);
    PH(T,     0, 1, T + 1, 1, 1, 1, -1);
    PH(T,     1, 0, T + 2, 0, 0, 1, -1);
    PH(T,     1, 1, T + 2, 0, 1, 1,  4);
    PH(T + 1, 0, 0, T + 2, 1, 0, 1, -1);
    PH(T + 1, 0, 1, T + 2, 1, 1, 1, -1);
    PH(T + 1, 1, 0, T + 3, 0, 0, 1, -1);
    PH(T + 1, 1, 1, T + 3, 0, 1, 1,  4);
  }
  // peeled last pair (T=62,63): finish staging t63, drain, no further stages
  PH(62, 0, 0, 63, 1, 0, 1, -1);
  PH(62, 0, 1, 63, 1, 1, 1, -1);
  PH(62, 1, 0,  0, 0, 0, 0, -1);
  PH(62, 1, 1,  0, 0, 0, 0,  0);
  PH(63, 0, 0,  0, 0, 0, 0, -1);
  PH(63, 0, 1,  0, 0, 0, 0, -1);
  PH(63, 1, 0,  0, 0, 0, 0, -1);
  PH(63, 1, 1,  0, 0, 0, 0, -1);
#undef PH

  // epilogue: mf rows = (mf>>2)*128 + wr*64 + (mf&3)*16; nf cols analog
#pragma unroll
  for (int mf = 0; mf < 8; ++mf)
#pragma unroll
    for (int nf = 0; nf < 4; ++nf)
#pragma unroll
      for (int r = 0; r < 4; ++r) {
        const int row = rowBase + (mf >> 2) * 128 + wr * 64 + (mf & 3) * 16 + lhi * 4 + r;
        const int col = colBase + (nf >> 1) * 128 + wc * 32 + (nf & 1) * 16 + llo;
        const float v = acc[mf][nf][r] * scl;
        if (OUTF) reinterpret_cast<float*>(Cout)[(size_t)row * HDIM + col] = v;
        else      reinterpret_cast<u16*>(Cout)[(size_t)row * HDIM + col] = f2bf(v);
      }
}

// ---------------- flash-causal attention (unchanged from R4) ----------------
__global__ __launch_bounds__(512, 4)
void attn_causal(const u16* __restrict__ Q, const u16* __restrict__ K,
                 const u16* __restrict__ VT, u16* __restrict__ O) {
  __shared__ __align__(16) u16 Ks[32][136];
  __shared__ __align__(16) u16 Vt[128][40];
  __shared__ __align__(16) u16 Pw[8][16][36];

  const int tid = threadIdx.x;
  const int w = tid >> 6, lane = tid & 63;
  const int lhi = lane >> 4, llo = lane & 15;
  const int bh = blockIdx.y, b = bh >> 5, h = bh & 31;

  const int x = blockIdx.x, kcl = blockIdx.y >> 4;
  int s;
  if (kcl == 0)      s = x;
  else if (kcl == 1) s = 15 - x;
  else if (kcl == 2) s = (x + 8) & 15;
  else               s = (7 - x) & 15;
  const int qb = s * QBLK;

  const u16* Qg = Q + ((size_t)(b * SEQ + qb)) * HDIM + h * DHEAD;
  const u16* Kg = K + ((size_t)b * SEQ) * HDIM + h * DHEAD;
  const u16* VTg = VT + (size_t)(h * DHEAD) * NROWS + b * SEQ;

  short8 qf[4];
#pragma unroll
  for (int dc = 0; dc < 4; ++dc)
    qf[dc] = *reinterpret_cast<const short8*>(Qg + (size_t)(w * 16 + llo) * HDIM + dc * 32 + lhi * 8);

  f32x4 o[8];
#pragma unroll
  for (int dt = 0; dt < 8; ++dt) o[dt] = (f32x4)0.0f;
  float mrow[4], lrow[4];
#pragma unroll
  for (int r = 0; r < 4; ++r) { mrow[r] = -__builtin_inff(); lrow[r] = 0.0f; }

  const int kr = tid >> 4, kch = tid & 15;
  const int vd = tid >> 2, vko = tid & 3;

  const float smul = 0.08838834764831845f;
  const int wmax = qb + w * 16 + 15;
  const int ntile = (qb + QBLK) / 32;

  short8 kreg = *reinterpret_cast<const short8*>(Kg + (size_t)kr * HDIM + kch * 8);
  short8 vreg = *reinterpret_cast<const short8*>(VTg + (size_t)vd * NROWS + vko * 8);

  for (int t = 0; t < ntile; ++t) {
    const int kv0 = t * 32;
    __syncthreads();
    *reinterpret_cast<short8*>(&Ks[kr][kch * 8]) = kreg;
    *reinterpret_cast<short8*>(&Vt[vd][vko * 8]) = vreg;
    if (t + 1 < ntile) {
      kreg = *reinterpret_cast<const short8*>(Kg + (size_t)(kv0 + 32 + kr) * HDIM + kch * 8);
      vreg = *reinterpret_cast<const short8*>(VTg + (size_t)vd * NROWS + kv0 + 32 + vko * 8);
    }
    __syncthreads();

    if (kv0 <= wmax) {
      f32x4 sacc[2];
      sacc[0] = (f32x4)0.0f; sacc[1] = (f32x4)0.0f;
      __builtin_amdgcn_s_setprio(1);
#pragma unroll
      for (int nt2 = 0; nt2 < 2; ++nt2)
#pragma unroll
        for (int dc = 0; dc < 4; ++dc) {
          const short8 kf = *reinterpret_cast<const short8*>(&Ks[nt2 * 16 + llo][dc * 32 + lhi * 8]);
          sacc[nt2] = __builtin_amdgcn_mfma_f32_16x16x32_bf16(qf[dc], kf, sacc[nt2], 0, 0, 0);
        }
      __builtin_amdgcn_s_setprio(0);

      float sv[2][4];
#pragma unroll
      for (int nt2 = 0; nt2 < 2; ++nt2)
#pragma unroll
        for (int r = 0; r < 4; ++r) {
          const int kcol = kv0 + nt2 * 16 + llo;
          const int qrow = qb + w * 16 + lhi * 4 + r;
          const float xv = sacc[nt2][r] * smul;
          sv[nt2][r] = (kcol <= qrow) ? xv : -__builtin_inff();
        }
      float rmax[4];
#pragma unroll
      for (int r = 0; r < 4; ++r) rmax[r] = fmaxf(sv[0][r], sv[1][r]);
#pragma unroll
      for (int xm = 1; xm < 16; xm <<= 1)
#pragma unroll
        for (int r = 0; r < 4; ++r) rmax[r] = fmaxf(rmax[r], __shfl_xor(rmax[r], xm));
      float p[2][4], fac[4], rsum[4];
#pragma unroll
      for (int r = 0; r < 4; ++r) {
        const float mn = fmaxf(mrow[r], rmax[r]);
        fac[r] = __expf(mrow[r] - mn);
        mrow[r] = mn;
        p[0][r] = __expf(sv[0][r] - mn);
        p[1][r] = __expf(sv[1][r] - mn);
        rsum[r] = p[0][r] + p[1][r];
      }
#pragma unroll
      for (int xm = 1; xm < 16; xm <<= 1)
#pragma unroll
        for (int r = 0; r < 4; ++r) rsum[r] += __shfl_xor(rsum[r], xm);
#pragma unroll
      for (int r = 0; r < 4; ++r) lrow[r] = lrow[r] * fac[r] + rsum[r];
#pragma unroll
      for (int dt = 0; dt < 8; ++dt)
#pragma unroll
        for (int r = 0; r < 4; ++r) o[dt][r] *= fac[r];

#pragma unroll
      for (int nt2 = 0; nt2 < 2; ++nt2)
#pragma unroll
        for (int r = 0; r < 4; ++r)
          Pw[w][lhi * 4 + r][nt2 * 16 + llo] = f2bf(p[nt2][r]);

      union { short4v hh[2]; short8 v8; } pu;
      pu.hh[0] = *reinterpret_cast<const short4v*>(&Pw[w][llo][lhi * 8]);
      pu.hh[1] = *reinterpret_cast<const short4v*>(&Pw[w][llo][lhi * 8 + 4]);
      __builtin_amdgcn_s_setprio(1);
#pragma unroll
      for (int dt = 0; dt < 8; ++dt) {
        const short8 vf = *reinterpret_cast<const short8*>(&Vt[dt * 16 + llo][lhi * 8]);
        o[dt] = __builtin_amdgcn_mfma_f32_16x16x32_bf16(pu.v8, vf, o[dt], 0, 0, 0);
      }
      __builtin_amdgcn_s_setprio(0);
    }
  }

  u16* Og = O + ((size_t)(b * SEQ + qb)) * HDIM + h * DHEAD;
  float inv[4];
#pragma unroll
  for (int r = 0; r < 4; ++r) inv[r] = 1.0f / lrow[r];
#pragma unroll
  for (int dt = 0; dt < 8; ++dt)
#pragma unroll
    for (int r = 0; r < 4; ++r)
      Og[(size_t)(w * 16 + lhi * 4 + r) * HDIM + dt * 16 + llo] = f2bf(o[dt][r] * inv[r]);
}

// ---------------- launch ----------------
extern "C" void kernel_launch(void* const* d_in, const int* in_sizes, int n_in,
                              void* d_out, int out_size, void* d_ws, size_t ws_size,
                              hipStream_t stream) {
  (void)in_sizes; (void)n_in; (void)out_size; (void)ws_size;
  const float* hs = (const float*)d_in[0];
  const float* wq = (const float*)d_in[2];
  const float* wk = (const float*)d_in[3];
  const float* wv = (const float*)d_in[4];
  const float* wo = (const float*)d_in[5];
  const float* sq = (const float*)d_in[6];
  const float* sk = (const float*)d_in[7];
  const float* sv = (const float*)d_in[8];
  const float* so = (const float*)d_in[9];

  char* p = (char*)d_ws;
  const size_t MAT = (size_t)NROWS * HDIM * sizeof(u16);  // 32 MiB
  u16* Xb = (u16*)p; p += MAT;   // X bf16; later attention output
  u16* Wb = (u16*)p; p += MAT;   // weight bf16 slot (reused 4x)
  u16* Qb = (u16*)p; p += MAT;
  u16* Kb = (u16*)p; p += MAT;
  u16* Vb = (u16*)p; p += MAT;   // holds V^T (operand-swapped GEMM output)
  float* cosT = (float*)p; p += (size_t)SEQ * 64 * sizeof(float);
  float* sinT = (float*)p; p += (size_t)SEQ * 64 * sizeof(float);

  const int n4 = NROWS * (HDIM / 4);
  const dim3 cb(256);
  const int LDSZ = 131072;  // 128 KiB dynamic LDS for gemm8
  (void)hipFuncSetAttribute(reinterpret_cast<const void*>(&gemm8<0>),
                            hipFuncAttributeMaxDynamicSharedMemorySize, LDSZ);
  (void)hipFuncSetAttribute(reinterpret_cast<const void*>(&gemm8<1>),
                            hipFuncAttributeMaxDynamicSharedMemorySize, LDSZ);

  f2bf_vec<<<dim3(2048), cb, 0, stream>>>(hs, Xb, n4);
  rope_tables_k<<<dim3((SEQ * 64 + 255) / 256), cb, 0, stream>>>(cosT, sinT);

  f2bf_vec<<<dim3(2048), cb, 0, stream>>>(wq, Wb, n4);
  gemm8<0><<<dim3(256), dim3(512), LDSZ, stream>>>(Xb, Wb, (void*)Qb, sq);
  f2bf_vec<<<dim3(2048), cb, 0, stream>>>(wk, Wb, n4);
  gemm8<0><<<dim3(256), dim3(512), LDSZ, stream>>>(Xb, Wb, (void*)Kb, sk);
  f2bf_vec<<<dim3(2048), cb, 0, stream>>>(wv, Wb, n4);
  // operand-swapped: C[o][r] = sum_k Wv[o][k] X[r][k] = V^T  (into Vb)
  gemm8<0><<<dim3(256), dim3(512), LDSZ, stream>>>(Wb, Xb, (void*)Vb, sv);

  rope_apply<<<dim3(NROWS, 2), cb, 0, stream>>>(Qb, Kb, cosT, sinT);
  attn_causal<<<dim3(SEQ / QBLK, NBATCH * NHEADS), dim3(512), 0, stream>>>(Qb, Kb, Vb, Xb);

  f2bf_vec<<<dim3(2048), cb, 0, stream>>>(wo, Wb, n4);
  gemm8<1><<<dim3(256), dim3(512), LDSZ, stream>>>(Xb, Wb, d_out, so);
}

// Round 7
// 754.524 us; speedup vs baseline: 2.2446x; 1.1217x over previous
//
#include <hip/hip_runtime.h>
#include <stdint.h>
#include <math.h>

// BitNetAttention on MI355X (gfx950), round 6: attention restructure.
// Triangle-fold pairing (block x does q-tiles x and 15-x: equal work per
// block at wave granularity), KVBLK=64 (half the barriers/staging iters),
// K via global_load_lds double-buffer with XOR source-swizzle (rule #21),
// V reg-staged (T14), Pw pitch 76. GEMM (8-phase 256^2) unchanged from R5.

#define HDIM   4096
#define SEQ    2048
#define NBATCH 2
#define NROWS  (NBATCH * SEQ)   // 4096
#define NHEADS 32
#define DHEAD  128
#define QBLK   128

typedef __attribute__((ext_vector_type(8))) short short8;
typedef __attribute__((ext_vector_type(4))) short short4v;
typedef __attribute__((ext_vector_type(4))) float f32x4;
typedef unsigned short u16;
typedef unsigned int   u32;

__device__ __forceinline__ float bf2f(u16 u) {
  union { float f; u32 i; } x; x.i = ((u32)u) << 16; return x.f;
}
__device__ __forceinline__ u16 f2bf(float f) {
  union { float f; u32 i; } x; x.f = f;
  u32 r = x.i + 0x7FFFu + ((x.i >> 16) & 1u);   // RNE
  return (u16)(r >> 16);
}

__device__ __forceinline__ void gload16(const u16* g, u16* l) {
  __builtin_amdgcn_global_load_lds(
      (const __attribute__((address_space(1))) u32*)g,
      (__attribute__((address_space(3))) u32*)l, 16, 0, 0);
}

__device__ __forceinline__ void unpack2(u32 v, float& a, float& b) {
  a = bf2f((u16)(v & 0xffffu)); b = bf2f((u16)(v >> 16));
}
__device__ __forceinline__ u32 pack2(float a, float b) {
  return (u32)f2bf(a) | ((u32)f2bf(b) << 16);
}

// ---------------- fp32 -> bf16 convert (vectorized) ----------------
__global__ void f2bf_vec(const float* __restrict__ in, u16* __restrict__ out, int n4) {
  int i = blockIdx.x * blockDim.x + threadIdx.x;
  const int stride = gridDim.x * blockDim.x;
  for (; i < n4; i += stride) {
    float4 v = reinterpret_cast<const float4*>(in)[i];
    u32 lo = (u32)f2bf(v.x) | ((u32)f2bf(v.y) << 16);
    u32 hi = (u32)f2bf(v.z) | ((u32)f2bf(v.w) << 16);
    reinterpret_cast<uint2*>(out)[i] = make_uint2(lo, hi);
  }
}

// ---------------- RoPE tables [SEQ][64] fp32 ----------------
__global__ void rope_tables_k(float* __restrict__ cosT, float* __restrict__ sinT) {
  int idx = blockIdx.x * blockDim.x + threadIdx.x;
  if (idx >= SEQ * 64) return;
  int s = idx >> 6, d = idx & 63;
  float ex = (float)(2 * d) / 128.0f;
  float inv = powf(10000.0f, -ex);
  float f = (float)s * inv;
  cosT[idx] = cosf(f);
  sinT[idx] = sinf(f);
}

// ---------------- RoPE apply in-place on bf16 Q/K (vectorized) ----------------
__global__ void rope_apply(u16* __restrict__ Q, u16* __restrict__ K,
                           const float* __restrict__ cosT, const float* __restrict__ sinT) {
  const int row = blockIdx.x;
  u16* T = (blockIdx.y == 0) ? Q : K;
  const int pos = row & (SEQ - 1);
  for (int i = threadIdx.x; i < NHEADS * 16; i += blockDim.x) {
    const int hd = i >> 4, d0 = (i & 15) * 4;
    const size_t base = (size_t)row * HDIM + hd * DHEAD + d0;
    uint2 alo = *reinterpret_cast<const uint2*>(&T[base]);
    uint2 ahi = *reinterpret_cast<const uint2*>(&T[base + 64]);
    float4 c4 = *reinterpret_cast<const float4*>(&cosT[pos * 64 + d0]);
    float4 s4 = *reinterpret_cast<const float4*>(&sinT[pos * 64 + d0]);
    float l0, l1, l2, l3, h0, h1, h2, h3;
    unpack2(alo.x, l0, l1); unpack2(alo.y, l2, l3);
    unpack2(ahi.x, h0, h1); unpack2(ahi.y, h2, h3);
    uint2 olo, ohi;
    olo.x = pack2(l0 * c4.x - h0 * s4.x, l1 * c4.y - h1 * s4.y);
    olo.y = pack2(l2 * c4.z - h2 * s4.z, l3 * c4.w - h3 * s4.w);
    ohi.x = pack2(h0 * c4.x + l0 * s4.x, h1 * c4.y + l1 * s4.y);
    ohi.y = pack2(h2 * c4.z + l2 * s4.z, h3 * c4.w + l3 * s4.w);
    *reinterpret_cast<uint2*>(&T[base]) = olo;
    *reinterpret_cast<uint2*>(&T[base + 64]) = ohi;
  }
}

// ---------------- 8-phase GEMM: C[4096][4096] = (A * B^T) * scale ----------------
template<int OUTF>
__global__ __launch_bounds__(512, 2)
void gemm8(const u16* __restrict__ Am, const u16* __restrict__ Bm,
           void* __restrict__ Cout, const float* __restrict__ scale_ptr) {
  extern __shared__ __align__(16) u16 ldsp[];

  const int tid = threadIdx.x;
  const int w = tid >> 6, lane = tid & 63;
  const int llo = lane & 15, lhi = (lane >> 4) & 3;
  const int wr = w >> 2, wc = w & 3;           // 2 x 4 waves

  const int bid = blockIdx.x;
  const int xcd = bid & 7, ii = bid >> 3;
  const int by = (xcd >> 1) * 4 + (ii & 3);
  const int bx = (xcd & 1) * 8 + (ii >> 2);
  const int rowBase = by * 256, colBase = bx * 256;
  const float scl = scale_ptr[0];

  auto stage_half = [&](const u16* G, int obase, int ts, int h, int opB) {
    const int p = ts & 1;
    const u32 base = (opB ? 32768u : 0u) + (u32)p * 16384u + (u32)h * 8192u;
#pragma unroll
    for (int i = 0; i < 2; ++i) {
      const int ru = i * 64 + w * 8;
      const int r = ru + (lane >> 3);
      const int cc = (lane & 7) ^ (r & 7);
      gload16(G + (size_t)(obase + h * 128 + r) * HDIM + ts * 64 + cc * 8,
              ldsp + base + (u32)ru * 64u);
    }
  };

  f32x4 acc[8][4];
#pragma unroll
  for (int m = 0; m < 8; ++m)
#pragma unroll
    for (int n = 0; n < 4; ++n) acc[m][n] = (f32x4)0.0f;

#define PH(TCUR, MH, NH, TS, H, OPB, DOSTAGE, VMN) do {                          \
    const int p_ = (TCUR) & 1;                                                   \
    short8 af_[4][2]; short8 bf_[2][2];                                          \
    const u32 ab_ = (u32)(p_ * 16384 + (MH) * 8192);                             \
    const u32 bb_ = (u32)(32768 + p_ * 16384 + (NH) * 8192);                     \
    _Pragma("unroll")                                                            \
    for (int m4 = 0; m4 < 4; ++m4) { const int r_ = wr * 64 + m4 * 16 + llo;     \
      _Pragma("unroll")                                                          \
      for (int kk = 0; kk < 2; ++kk) { const int c_ = kk * 4 + lhi;              \
        af_[m4][kk] = *reinterpret_cast<const short8*>(                          \
            ldsp + ab_ + r_ * 64 + ((c_ ^ (r_ & 7)) * 8)); } }                   \
    _Pragma("unroll")                                                            \
    for (int n2 = 0; n2 < 2; ++n2) { const int r_ = wc * 32 + n2 * 16 + llo;     \
      _Pragma("unroll")                                                          \
      for (int kk = 0; kk < 2; ++kk) { const int c_ = kk * 4 + lhi;              \
        bf_[n2][kk] = *reinterpret_cast<const short8*>(                          \
            ldsp + bb_ + r_ * 64 + ((c_ ^ (r_ & 7)) * 8)); } }                   \
    if (DOSTAGE) stage_half((OPB) ? Bm : Am, (OPB) ? colBase : rowBase,          \
                            (TS), (H), (OPB));                                   \
    __builtin_amdgcn_s_barrier();                                                \
    asm volatile("s_waitcnt lgkmcnt(0)" ::: "memory");                           \
    __builtin_amdgcn_s_setprio(1);                                               \
    _Pragma("unroll")                                                            \
    for (int m4 = 0; m4 < 4; ++m4)                                               \
      _Pragma("unroll")                                                          \
      for (int n2 = 0; n2 < 2; ++n2)                                             \
        _Pragma("unroll")                                                        \
        for (int kk = 0; kk < 2; ++kk)                                           \
          acc[(MH) * 4 + m4][(NH) * 2 + n2] =                                    \
              __builtin_amdgcn_mfma_f32_16x16x32_bf16(                           \
                  af_[m4][kk], bf_[n2][kk],                                      \
                  acc[(MH) * 4 + m4][(NH) * 2 + n2], 0, 0, 0);                   \
    __builtin_amdgcn_s_setprio(0);                                               \
    if ((VMN) == 4) asm volatile("s_waitcnt vmcnt(4)" ::: "memory");             \
    if ((VMN) == 0) asm volatile("s_waitcnt vmcnt(0)" ::: "memory");             \
    __builtin_amdgcn_s_barrier();                                                \
  } while (0)

  stage_half(Am, rowBase, 0, 0, 0);
  stage_half(Bm, colBase, 0, 0, 1);
  stage_half(Am, rowBase, 0, 1, 0);
  stage_half(Bm, colBase, 0, 1, 1);
  stage_half(Am, rowBase, 1, 0, 0);
  stage_half(Bm, colBase, 1, 0, 1);
  asm volatile("s_waitcnt vmcnt(4)" ::: "memory");
  __builtin_amdgcn_s_barrier();

  for (int it = 0; it < 31; ++it) {
    const int T = 2 * it;
    PH(T,     0, 0, T + 1, 1, 0, 1, -1);
    PH(T,     0, 1, T + 1, 1, 1, 1, -1);
    PH(T,     1, 0, T + 2, 0, 0, 1, -1);
    PH(T,     1, 1, T + 2, 0, 1, 1,  4);
    PH(T + 1, 0, 0, T + 2, 1, 0, 1, -1);
    PH(T + 1, 0, 1, T + 2, 1, 1, 1, -1);
    PH(T + 1, 1, 0, T + 3, 0, 0, 1, -1);
    PH(T + 1, 1, 1, T + 3, 0, 1, 1,  4);
  }
  PH(62, 0, 0, 63, 1, 0, 1, -1);
  PH(62, 0, 1, 63, 1, 1, 1, -1);
  PH(62, 1, 0,  0, 0, 0, 0, -1);
  PH(62, 1, 1,  0, 0, 0, 0,  0);
  PH(63, 0, 0,  0, 0, 0, 0, -1);
  PH(63, 0, 1,  0, 0, 0, 0, -1);
  PH(63, 1, 0,  0, 0, 0, 0, -1);
  PH(63, 1, 1,  0, 0, 0, 0, -1);
#undef PH

#pragma unroll
  for (int mf = 0; mf < 8; ++mf)
#pragma unroll
    for (int nf = 0; nf < 4; ++nf)
#pragma unroll
      for (int r = 0; r < 4; ++r) {
        const int row = rowBase + (mf >> 2) * 128 + wr * 64 + (mf & 3) * 16 + lhi * 4 + r;
        const int col = colBase + (nf >> 1) * 128 + wc * 32 + (nf & 1) * 16 + llo;
        const float v = acc[mf][nf][r] * scl;
        if (OUTF) reinterpret_cast<float*>(Cout)[(size_t)row * HDIM + col] = v;
        else      reinterpret_cast<u16*>(Cout)[(size_t)row * HDIM + col] = f2bf(v);
      }
}

// ---------------- flash-causal attention ----------------
// Grid (8, 64); block x does q-tiles x and 15-x (equal work: triangle fold).
// KVBLK=64. K: global_load_lds double-buffer, XOR source-swizzle cs=c^(r&7).
// V: reg-staged (T14) into Vt[128][72]. Pw pitch 76 (conflict-free stores).
__global__ __launch_bounds__(512, 4)
void attn_causal(const u16* __restrict__ Q, const u16* __restrict__ K,
                 const u16* __restrict__ VT, u16* __restrict__ O) {
  __shared__ __align__(16) u16 Ks[2][64][128];
  __shared__ __align__(16) u16 Vt[128][72];
  __shared__ __align__(16) u16 Pw[8][16][76];

  const int tid = threadIdx.x;
  const int w = tid >> 6, lane = tid & 63;
  const int lhi = lane >> 4, llo = lane & 15;
  const int bh = blockIdx.y, b = bh >> 5, h = bh & 31;

  const u16* Kg = K + ((size_t)b * SEQ) * HDIM + h * DHEAD;
  const u16* VTg = VT + (size_t)(h * DHEAD) * NROWS + b * SEQ;   // [d][s], stride NROWS

  // K gload_lds mapping: i-th load dest byte = i*8192 + tid*16 ->
  // (row r = i*32 + (tid>>4), LDS chunk c' = tid&15); source chunk = c'^(r&7).
  const int krr[2] = { (tid >> 4), 32 + (tid >> 4) };
  const int kcp = tid & 15;
  // V: vd row, chunks vko and vko+4 (two 32-kv halves per tile)
  const int vd = tid >> 2, vko = tid & 3;

  const float smul = 0.08838834764831845f;   // 1/sqrt(128)
  int buf = 0;

  auto issueK = [&](int kv0, int bsel) {
#pragma unroll
    for (int i = 0; i < 2; ++i) {
      const int r = krr[i];
      const int cs = kcp ^ (r & 7);
      gload16(Kg + (size_t)(kv0 + r) * HDIM + cs * 8,
              &Ks[bsel][i * 32 + (tid >> 4) & 31][0] - ((tid >> 4) & 31) * 128 + ((size_t)0));
    }
  };
  (void)issueK;  // replaced below by explicit form (wave-uniform dest arithmetic)

  for (int halfq = 0; halfq < 2; ++halfq) {
    const int xq = (halfq == 0) ? (int)blockIdx.x : 15 - (int)blockIdx.x;
    const int qb = xq * QBLK;
    const int ntile = qb / 64 + 2;
    const int wmax = qb + w * 16 + 15;

    const u16* Qg = Q + ((size_t)(b * SEQ + qb)) * HDIM + h * DHEAD;
    short8 qf[4];
#pragma unroll
    for (int dc = 0; dc < 4; ++dc)
      qf[dc] = *reinterpret_cast<const short8*>(Qg + (size_t)(w * 16 + llo) * HDIM + dc * 32 + lhi * 8);

    f32x4 o[8];
#pragma unroll
    for (int dt = 0; dt < 8; ++dt) o[dt] = (f32x4)0.0f;
    float mrow[4], lrow[4];
#pragma unroll
    for (int r = 0; r < 4; ++r) { mrow[r] = -__builtin_inff(); lrow[r] = 0.0f; }

    // prologue: stage K(0) into Ks[buf]; V(0) -> regs
    {
      u16* dst = &Ks[buf][0][0] + tid * 8;           // dest = tid*16 bytes
#pragma unroll
      for (int i = 0; i < 2; ++i) {
        const int r = i * 32 + (tid >> 4);
        const int cs = kcp ^ (r & 7);
        gload16(Kg + (size_t)r * HDIM + cs * 8, dst + i * 4096);
      }
    }
    short8 vreg0 = *reinterpret_cast<const short8*>(VTg + (size_t)vd * NROWS + vko * 8);
    short8 vreg1 = *reinterpret_cast<const short8*>(VTg + (size_t)vd * NROWS + 32 + vko * 8);

    for (int t = 0; t < ntile; ++t) {
      const int kv0 = t * 64;
      __syncthreads();   // drains K(t)/V(t) loads; prev tile's LDS reads done
      *reinterpret_cast<short8*>(&Vt[vd][vko * 8]) = vreg0;
      *reinterpret_cast<short8*>(&Vt[vd][32 + vko * 8]) = vreg1;
      __syncthreads();   // Vt(t) + Ks[buf](t) visible
      if (t + 1 < ntile) {
        const int nkv = kv0 + 64;
        u16* dst = &Ks[buf ^ 1][0][0] + tid * 8;
#pragma unroll
        for (int i = 0; i < 2; ++i) {
          const int r = i * 32 + (tid >> 4);
          const int cs = kcp ^ (r & 7);
          gload16(Kg + (size_t)(nkv + r) * HDIM + cs * 8, dst + i * 4096);
        }
        vreg0 = *reinterpret_cast<const short8*>(VTg + (size_t)vd * NROWS + nkv + vko * 8);
        vreg1 = *reinterpret_cast<const short8*>(VTg + (size_t)vd * NROWS + nkv + 32 + vko * 8);
      }

      if (kv0 <= wmax) {
        f32x4 sacc[4];
#pragma unroll
        for (int nt2 = 0; nt2 < 4; ++nt2) sacc[nt2] = (f32x4)0.0f;
        __builtin_amdgcn_s_setprio(1);
#pragma unroll
        for (int nt2 = 0; nt2 < 4; ++nt2) {
          const int r = nt2 * 16 + llo;
#pragma unroll
          for (int dc = 0; dc < 4; ++dc) {
            const int cs = (dc * 4 + lhi) ^ (r & 7);
            const short8 kf = *reinterpret_cast<const short8*>(&Ks[buf][r][cs * 8]);
            sacc[nt2] = __builtin_amdgcn_mfma_f32_16x16x32_bf16(qf[dc], kf, sacc[nt2], 0, 0, 0);
          }
        }
        __builtin_amdgcn_s_setprio(0);

        float sv[4][4];
#pragma unroll
        for (int nt2 = 0; nt2 < 4; ++nt2)
#pragma unroll
          for (int r = 0; r < 4; ++r) {
            const int kcol = kv0 + nt2 * 16 + llo;
            const int qrow = qb + w * 16 + lhi * 4 + r;
            const float xv = sacc[nt2][r] * smul;
            sv[nt2][r] = (kcol <= qrow) ? xv : -__builtin_inff();
          }
        float rmax[4];
#pragma unroll
        for (int r = 0; r < 4; ++r)
          rmax[r] = fmaxf(fmaxf(sv[0][r], sv[1][r]), fmaxf(sv[2][r], sv[3][r]));
#pragma unroll
        for (int xm = 1; xm < 16; xm <<= 1)
#pragma unroll
          for (int r = 0; r < 4; ++r) rmax[r] = fmaxf(rmax[r], __shfl_xor(rmax[r], xm));
        float p[4][4], fac[4], rsum[4];
#pragma unroll
        for (int r = 0; r < 4; ++r) {
          const float mn = fmaxf(mrow[r], rmax[r]);
          fac[r] = __expf(mrow[r] - mn);
          mrow[r] = mn;
          p[0][r] = __expf(sv[0][r] - mn);
          p[1][r] = __expf(sv[1][r] - mn);
          p[2][r] = __expf(sv[2][r] - mn);
          p[3][r] = __expf(sv[3][r] - mn);
          rsum[r] = (p[0][r] + p[1][r]) + (p[2][r] + p[3][r]);
        }
#pragma unroll
        for (int xm = 1; xm < 16; xm <<= 1)
#pragma unroll
          for (int r = 0; r < 4; ++r) rsum[r] += __shfl_xor(rsum[r], xm);
#pragma unroll
        for (int r = 0; r < 4; ++r) lrow[r] = lrow[r] * fac[r] + rsum[r];
#pragma unroll
        for (int dt = 0; dt < 8; ++dt)
#pragma unroll
          for (int r = 0; r < 4; ++r) o[dt][r] *= fac[r];

#pragma unroll
        for (int nt2 = 0; nt2 < 4; ++nt2)
#pragma unroll
          for (int r = 0; r < 4; ++r)
            Pw[w][lhi * 4 + r][nt2 * 16 + llo] = f2bf(p[nt2][r]);

        union { short4v hh[2]; short8 v8; } pu[2];
#pragma unroll
        for (int s = 0; s < 2; ++s) {
          pu[s].hh[0] = *reinterpret_cast<const short4v*>(&Pw[w][llo][s * 32 + lhi * 8]);
          pu[s].hh[1] = *reinterpret_cast<const short4v*>(&Pw[w][llo][s * 32 + lhi * 8 + 4]);
        }
        __builtin_amdgcn_s_setprio(1);
#pragma unroll
        for (int dt = 0; dt < 8; ++dt)
#pragma unroll
          for (int s = 0; s < 2; ++s) {
            const short8 vf = *reinterpret_cast<const short8*>(&Vt[dt * 16 + llo][s * 32 + lhi * 8]);
            o[dt] = __builtin_amdgcn_mfma_f32_16x16x32_bf16(pu[s].v8, vf, o[dt], 0, 0, 0);
          }
        __builtin_amdgcn_s_setprio(0);
      }
      buf ^= 1;
    }

    u16* Og = O + ((size_t)(b * SEQ + qb)) * HDIM + h * DHEAD;
    float inv[4];
#pragma unroll
    for (int r = 0; r < 4; ++r) inv[r] = 1.0f / lrow[r];
#pragma unroll
    for (int dt = 0; dt < 8; ++dt)
#pragma unroll
      for (int r = 0; r < 4; ++r)
        Og[(size_t)(w * 16 + lhi * 4 + r) * HDIM + dt * 16 + llo] = f2bf(o[dt][r] * inv[r]);
  }
}

// ---------------- launch ----------------
extern "C" void kernel_launch(void* const* d_in, const int* in_sizes, int n_in,
                              void* d_out, int out_size, void* d_ws, size_t ws_size,
                              hipStream_t stream) {
  (void)in_sizes; (void)n_in; (void)out_size; (void)ws_size;
  const float* hs = (const float*)d_in[0];
  const float* wq = (const float*)d_in[2];
  const float* wk = (const float*)d_in[3];
  const float* wv = (const float*)d_in[4];
  const float* wo = (const float*)d_in[5];
  const float* sq = (const float*)d_in[6];
  const float* sk = (const float*)d_in[7];
  const float* sv = (const float*)d_in[8];
  const float* so = (const float*)d_in[9];

  char* p = (char*)d_ws;
  const size_t MAT = (size_t)NROWS * HDIM * sizeof(u16);  // 32 MiB
  u16* Xb = (u16*)p; p += MAT;   // X bf16; later attention output
  u16* Wb = (u16*)p; p += MAT;   // weight bf16 slot (reused 4x)
  u16* Qb = (u16*)p; p += MAT;
  u16* Kb = (u16*)p; p += MAT;
  u16* Vb = (u16*)p; p += MAT;   // holds V^T (operand-swapped GEMM output)
  float* cosT = (float*)p; p += (size_t)SEQ * 64 * sizeof(float);
  float* sinT = (float*)p; p += (size_t)SEQ * 64 * sizeof(float);

  const int n4 = NROWS * (HDIM / 4);
  const dim3 cb(256);
  const int LDSZ = 131072;  // 128 KiB dynamic LDS for gemm8
  (void)hipFuncSetAttribute(reinterpret_cast<const void*>(&gemm8<0>),
                            hipFuncAttributeMaxDynamicSharedMemorySize, LDSZ);
  (void)hipFuncSetAttribute(reinterpret_cast<const void*>(&gemm8<1>),
                            hipFuncAttributeMaxDynamicSharedMemorySize, LDSZ);

  f2bf_vec<<<dim3(2048), cb, 0, stream>>>(hs, Xb, n4);
  rope_tables_k<<<dim3((SEQ * 64 + 255) / 256), cb, 0, stream>>>(cosT, sinT);

  f2bf_vec<<<dim3(2048), cb, 0, stream>>>(wq, Wb, n4);
  gemm8<0><<<dim3(256), dim3(512), LDSZ, stream>>>(Xb, Wb, (void*)Qb, sq);
  f2bf_vec<<<dim3(2048), cb, 0, stream>>>(wk, Wb, n4);
  gemm8<0><<<dim3(256), dim3(512), LDSZ, stream>>>(Xb, Wb, (void*)Kb, sk);
  f2bf_vec<<<dim3(2048), cb, 0, stream>>>(wv, Wb, n4);
  // operand-swapped: C[o][r] = sum_k Wv[o][k] X[r][k] = V^T  (into Vb)
  gemm8<0><<<dim3(256), dim3(512), LDSZ, stream>>>(Wb, Xb, (void*)Vb, sv);

  rope_apply<<<dim3(NROWS, 2), cb, 0, stream>>>(Qb, Kb, cosT, sinT);
  attn_causal<<<dim3(8, NBATCH * NHEADS), dim3(512), 0, stream>>>(Qb, Kb, Vb, Xb);

  f2bf_vec<<<dim3(2048), cb, 0, stream>>>(wo, Wb, n4);
  gemm8<1><<<dim3(256), dim3(512), LDSZ, stream>>>(Xb, Wb, d_out, so);
}